// Round 7
// baseline (1774.314 us; speedup 1.0000x reference)
//
#include <hip/hip_runtime.h>

typedef unsigned short u16;
typedef unsigned int u32;

#define P_PAIRS 160000
#define N_ATOMS 10000

#define OFF_WMLP  0
#define OFF_BMLP  3200
#define OFF_WE1   3250
#define OFF_BE1   6930
#define OFF_WE2   6962
#define OFF_BE2   7986
#define OFF_WATT  8018
#define OFF_BATT  8242
#define OFF_WN1   8249
#define OFF_BN1   17465
#define OFF_WN2   17497
#define OFF_BN2   18521
#define OFF_WP1   18553
#define OFF_BP1   25721
#define OFF_WP2   25753
#define OFF_BP2   26777
#define OFF_WV1   26809
#define OFF_BV1   27833
#define OFF_WV2   27865
#define OFF_WVMIX 27897
#define WF_TOTAL  28121

__device__ __forceinline__ float b2f(u16 u){ return __uint_as_float(((u32)u) << 16); }
__device__ __forceinline__ u16 f2b(float f){
  u32 u = __float_as_uint(f);
  u32 r = (u + 0x7FFFu + ((u >> 16) & 1u)) >> 16;
  return (u16)r;
}
__device__ __forceinline__ float siluf(float v){ return v / (1.f + __expf(-v)); }
__device__ __forceinline__ float ldw(const void* p, int o, int bf){
  return bf ? b2f(((const u16*)p)[o]) : ((const float*)p)[o];
}
__device__ __forceinline__ u32 fenc(float f){
  u32 u = __float_as_uint(f);
  return (u & 0x80000000u) ? ~u : (u | 0x80000000u);
}
__device__ __forceinline__ float fdec(u32 e){
  return (e & 0x80000000u) ? __uint_as_float(e & 0x7FFFFFFFu) : __uint_as_float(~e);
}

// ---------------- host-detected problem: write code to out[0] (fp32!) -------
__global__ void k_code(float* out, float code){
  if (threadIdx.x == 0 && blockIdx.x == 0) out[0] = code;
}

// ---------------- dtype detection ----------------
__global__ void k_detect(const u32* __restrict__ hw, const u32* __restrict__ plw,
                         int* __restrict__ flags){
  if (threadIdx.x == 0 && blockIdx.x == 0){
    int bf = 0;
    for (int k = 0; k < 64; ++k){
      u32 e = (hw[k] >> 7) & 0xFFu;
      if (e >= 100u && e <= 140u) bf++;
    }
    flags[0] = (bf >= 48) ? 1 : 0;
    int z = 0;
    for (int k = 0; k < 64; ++k) if (plw[2*k+1] == 0u) z++;
    flags[1] = (z >= 60) ? 1 : 0;
  }
}

// ---------------- input normalization (h,x,v -> fp32; pairlist -> int32) ----
__global__ void k_norm(const void* __restrict__ h_raw, const void* __restrict__ x_raw,
                       const void* __restrict__ v_raw, const void* __restrict__ pl_raw,
                       const int* __restrict__ flags, float* __restrict__ hf,
                       float* __restrict__ xf, float* __restrict__ vf, int* __restrict__ pli){
  int t = blockIdx.x * 256 + threadIdx.x;
  int bf = flags[0], i64 = flags[1];
  if (t < 320000){
    hf[t] = ldw(h_raw, t, bf);
  } else if (t < 350000){
    int i = t - 320000;
    xf[i] = ldw(x_raw, i, bf);
  } else if (t < 380000){
    int i = t - 350000;
    vf[i] = ldw(v_raw, i, bf);
  } else if (t < 700000){
    int k = t - 380000;
    const int* p32 = (const int*)pl_raw;
    pli[k] = i64 ? p32[2*(size_t)k] : p32[k];
  }
}

// ---------------- weight conversion -> fp32 ----------------
__global__ void k_convert(const void* w_mlp, const void* b_mlp, const void* w_e1, const void* b_e1,
  const void* w_e2, const void* b_e2, const void* w_att, const void* b_att,
  const void* w_n1, const void* b_n1, const void* w_n2, const void* b_n2,
  const void* w_p1, const void* b_p1, const void* w_p2, const void* b_p2,
  const void* w_v1, const void* b_v1, const void* w_v2, const void* w_vmix,
  const int* __restrict__ flags, float* __restrict__ Wf){
  int t = blockIdx.x * 256 + threadIdx.x;
  if (t >= WF_TOTAL) return;
  int bf = flags[0];
  const void* src; int o;
  if      (t < 3200)  { src = w_mlp;  o = t; }
  else if (t < 3250)  { src = b_mlp;  o = t - 3200; }
  else if (t < 6930)  { src = w_e1;   o = t - 3250; }
  else if (t < 6962)  { src = b_e1;   o = t - 6930; }
  else if (t < 7986)  { src = w_e2;   o = t - 6962; }
  else if (t < 8018)  { src = b_e2;   o = t - 7986; }
  else if (t < 8242)  { src = w_att;  o = t - 8018; }
  else if (t < 8249)  { src = b_att;  o = t - 8242; }
  else if (t < 17465) { src = w_n1;   o = t - 8249; }
  else if (t < 17497) { src = b_n1;   o = t - 17465; }
  else if (t < 18521) { src = w_n2;   o = t - 17497; }
  else if (t < 18553) { src = b_n2;   o = t - 18521; }
  else if (t < 25721) { src = w_p1;   o = t - 18553; }
  else if (t < 25753) { src = b_p1;   o = t - 25721; }
  else if (t < 26777) { src = w_p2;   o = t - 25753; }
  else if (t < 26809) { src = b_p2;   o = t - 26777; }
  else if (t < 27833) { src = w_v1;   o = t - 26809; }
  else if (t < 27865) { src = b_v1;   o = t - 27833; }
  else if (t < 27897) { src = w_v2;   o = t - 27865; }
  else                { src = w_vmix; o = t - 27897; }
  Wf[t] = ldw(src, o, bf);
}

__global__ void k_wx(const void* __restrict__ wx, const int* __restrict__ flags,
                     float* __restrict__ Wx){
  int t = blockIdx.x * 256 + threadIdx.x;
  if (t >= 224 * 224) return;
  Wx[t] = ldw(wx, t, flags[0]);
}

// ---------------- per-pair edge model ----------------
__global__ __launch_bounds__(256) void k_pair(const float* __restrict__ h, const float* __restrict__ x,
    const int* __restrict__ pl, const float* __restrict__ Wf,
    u16* __restrict__ edge, float* __restrict__ logits, float* __restrict__ dir){
  int tid = threadIdx.x;
  int p = blockIdx.x * 256 + tid;
  int i = pl[p], j = pl[P_PAIRS + p];
  const float* hi = h + i * 32;
  const float* hj = h + j * 32;
  float r0 = x[j*3+0] - x[i*3+0];
  float r1 = x[j*3+1] - x[i*3+1];
  float r2 = x[j*3+2] - x[i*3+2];
  float d = sqrtf(r0*r0 + r1*r1 + r2*r2);
  float rinv = 1.f / (d + 1e-5f);
  dir[p*3+0] = r0*rinv; dir[p*3+1] = r1*rinv; dir[p*3+2] = r2*rinv;

  float filt[50];
  #pragma unroll
  for (int o = 0; o < 50; ++o) filt[o] = Wf[OFF_BMLP + o];
  for (int k = 0; k < 64; ++k){
    float hk = (k < 32) ? hi[k] : hj[k - 32];
    const float* wr = Wf + OFF_WMLP + k * 50;
    #pragma unroll
    for (int o = 0; o < 50; ++o) filt[o] += hk * wr[o];
  }
  #pragma unroll
  for (int o = 0; o < 50; ++o){
    float c = (float)o * (5.0f / 49.0f);
    float dd = d - c;
    filt[o] *= __expf(-10.0f * dd * dd);
  }
  float u[32];
  #pragma unroll
  for (int o = 0; o < 32; ++o) u[o] = Wf[OFF_BE1 + o];
  for (int k = 0; k < 64; ++k){
    float ek = (k < 32) ? hi[k] : hj[k - 32];
    const float* wr = Wf + OFF_WE1 + k * 32;
    #pragma unroll
    for (int o = 0; o < 32; ++o) u[o] += ek * wr[o];
  }
  #pragma unroll
  for (int kk = 0; kk < 50; ++kk){
    const float* wr = Wf + OFF_WE1 + (64 + kk) * 32;
    #pragma unroll
    for (int o = 0; o < 32; ++o) u[o] += filt[kk] * wr[o];
  }
  {
    const float* wr = Wf + OFF_WE1 + 114 * 32;
    #pragma unroll
    for (int o = 0; o < 32; ++o) u[o] += d * wr[o];
  }
  #pragma unroll
  for (int o = 0; o < 32; ++o) u[o] = siluf(u[o]);
  float eg[32];
  #pragma unroll
  for (int o = 0; o < 32; ++o) eg[o] = Wf[OFF_BE2 + o];
  #pragma unroll
  for (int k = 0; k < 32; ++k){
    const float* wr = Wf + OFF_WE2 + k * 32;
    #pragma unroll
    for (int o = 0; o < 32; ++o) eg[o] += u[k] * wr[o];
  }
  {
    u32 st[16];
    #pragma unroll
    for (int o = 0; o < 16; ++o)
      st[o] = (u32)f2b(eg[2*o]) | ((u32)f2b(eg[2*o+1]) << 16);
    #pragma unroll
    for (int q = 0; q < 4; ++q){
      uint4 vv; vv.x = st[4*q]; vv.y = st[4*q+1]; vv.z = st[4*q+2]; vv.w = st[4*q+3];
      *(uint4*)(edge + (size_t)p * 32 + q * 8) = vv;
    }
  }
  float lg[7];
  #pragma unroll
  for (int o = 0; o < 7; ++o) lg[o] = Wf[OFF_BATT + o];
  #pragma unroll
  for (int k = 0; k < 32; ++k){
    const float* wr = Wf + OFF_WATT + k * 7;
    #pragma unroll
    for (int o = 0; o < 7; ++o) lg[o] += eg[k] * wr[o];
  }
  #pragma unroll
  for (int o = 0; o < 7; ++o){
    float vv = lg[o];
    float cl = vv > 0.f ? vv : 2.f * expm1f(0.5f * vv);
    logits[p*7+o] = cl;
  }
}

// ---------------- histogram ----------------
__global__ void k_hist(const int* __restrict__ pl, int* __restrict__ counts){
  int p = blockIdx.x * 256 + threadIdx.x;
  atomicAdd(&counts[pl[p]], 1);
}

// ---------------- softmax passes ----------------
__global__ void k_gmax(const int* __restrict__ pl, const float* __restrict__ logits,
                       u32* __restrict__ segmaxe){
  int p = blockIdx.x * 256 + threadIdx.x;
  int i = pl[p];
  #pragma unroll
  for (int hh = 0; hh < 7; ++hh)
    atomicMax(&segmaxe[i*7+hh], fenc(logits[p*7+hh]));
}

__global__ void k_gsum(const int* __restrict__ pl, const float* __restrict__ logits,
                       const u32* __restrict__ segmaxe, float* __restrict__ ebuf,
                       float* __restrict__ segsum){
  int p = blockIdx.x * 256 + threadIdx.x;
  int i = pl[p];
  #pragma unroll
  for (int hh = 0; hh < 7; ++hh){
    float m = fdec(segmaxe[i*7+hh]);
    float ev = __expf(logits[p*7+hh] - m);
    ebuf[p*7+hh] = ev;
    atomicAdd(&segsum[i*7+hh], ev);
  }
}

__global__ void k_inv(const float* __restrict__ segsum, float* __restrict__ invsum){
  int t = blockIdx.x * 256 + threadIdx.x;
  if (t < N_ATOMS * 7) invsum[t] = 1.f / segsum[t];
}

// literal att_agg: aggsum[i,h] = sum att ; invagg = 1/aggsum
__global__ void k_gagg(const int* __restrict__ pl, const float* __restrict__ ebuf,
                       const float* __restrict__ invsum, float* __restrict__ aggsum){
  int p = blockIdx.x * 256 + threadIdx.x;
  int i = pl[p];
  #pragma unroll
  for (int hh = 0; hh < 7; ++hh)
    atomicAdd(&aggsum[i*7+hh], ebuf[p*7+hh] * invsum[i*7+hh]);
}

__global__ void k_inv2(const float* __restrict__ aggsum, const int* __restrict__ counts,
                       float* __restrict__ invagg){
  int t = blockIdx.x * 256 + threadIdx.x;
  if (t < N_ATOMS * 7) invagg[t] = (counts[t/7] > 0) ? 1.f / aggsum[t] : 0.f;
}

// ---------------- GEMM + hsem & comb atomics ----------------
#define XLDS_BS   16896
#define XLDS_EL   45696
#define XLDS_AL   53888
#define XLDS_IL   57856
#define XLDS_DL   58368
#define XLDS_TOT  59904

__global__ __launch_bounds__(256) void k_xmix2(const int* __restrict__ pl,
    const u16* __restrict__ edge, const float* __restrict__ ebuf,
    const float* __restrict__ invsum, const float* __restrict__ invagg,
    const float* __restrict__ dir,
    const float* __restrict__ Wx, float* __restrict__ hsema, float* __restrict__ comb){
  __shared__ __attribute__((aligned(16))) char smem[XLDS_TOT];
  float* As = (float*)smem;
  float* Bs = (float*)(smem + XLDS_BS);
  u16*   eL = (u16*)(smem + XLDS_EL);
  float* aL = (float*)(smem + XLDS_AL);
  int*   iL = (int*)(smem + XLDS_IL);
  float* dL = (float*)(smem + XLDS_DL);
  int tid = threadIdx.x;
  int ty = tid >> 4, tx = tid & 15;
  int row0 = blockIdx.x * 128;

  if (tid < 128){
    iL[tid] = pl[row0 + tid];
    dL[tid*3+0] = dir[(row0+tid)*3+0];
    dL[tid*3+1] = dir[(row0+tid)*3+1];
    dL[tid*3+2] = dir[(row0+tid)*3+2];
  }
  for (int e = tid; e < 896; e += 256){
    int r = e / 7, hh = e - r * 7;
    int p = row0 + r;
    int i = pl[p];
    aL[e] = ebuf[(size_t)p*7 + hh] * invsum[i*7 + hh] * invagg[i*7 + hh];
  }
  for (int e = tid; e < 512; e += 256){
    int r = e >> 2, q = e & 3;
    *(uint4*)(eL + r*32 + q*8) = *(const uint4*)(edge + (size_t)(row0 + r)*32 + q*8);
  }
  float acc[8][14];
  #pragma unroll
  for (int rr = 0; rr < 8; ++rr)
    #pragma unroll
    for (int cc = 0; cc < 14; ++cc) acc[rr][cc] = 0.f;
  __syncthreads();

  for (int kt = 0; kt < 7; ++kt){
    int kk = kt * 32;
    for (int e = tid; e < 7168; e += 256){
      int k = e / 224, c = e - k * 224;
      Bs[k*225 + c] = Wx[(size_t)(kk + k) * 224 + c];
    }
    for (int e = tid; e < 4096; e += 256){
      int r = e >> 5, k = e & 31;
      int kc = kk + k;
      int f = kc / 7, hh = kc - f * 7;
      float v = b2f(eL[r*32 + f]) * aL[r*7 + hh];
      As[r*33 + k] = v;
      atomicAdd(&hsema[(size_t)iL[r]*224 + kc], v);
    }
    __syncthreads();
    #pragma unroll 4
    for (int k = 0; k < 32; ++k){
      float a[8], b[14];
      #pragma unroll
      for (int rr = 0; rr < 8; ++rr) a[rr] = As[(ty*8 + rr)*33 + k];
      #pragma unroll
      for (int cc = 0; cc < 14; ++cc) b[cc] = Bs[k*225 + tx*14 + cc];
      #pragma unroll
      for (int rr = 0; rr < 8; ++rr)
        #pragma unroll
        for (int cc = 0; cc < 14; ++cc) acc[rr][cc] = fmaf(a[rr], b[cc], acc[rr][cc]);
    }
    __syncthreads();
  }
  u16* xt = (u16*)smem;
  #pragma unroll
  for (int rr = 0; rr < 8; ++rr)
    #pragma unroll
    for (int cc = 0; cc < 14; ++cc){
      int r = ty*8 + rr, c = tx*14 + cc;
      float vv = acc[rr][cc];
      vv = fminf(fmaxf(vv, -15.f), 15.f);
      float e2 = __expf(2.f * vv);
      xt[r*226 + c] = f2b((e2 - 1.f) / (e2 + 1.f));
    }
  __syncthreads();
  if (tid < 224){
    int c = tid;
    for (int r = 0; r < 128; ++r){
      float xv = b2f(xt[r*226 + c]);
      int ai = iL[r];
      atomicAdd(&comb[((size_t)ai*224 + c)*3 + 0], dL[r*3+0] * xv);
      atomicAdd(&comb[((size_t)ai*224 + c)*3 + 1], dL[r*3+1] * xv);
      atomicAdd(&comb[((size_t)ai*224 + c)*3 + 2], dL[r*3+2] * xv);
    }
  }
}

// ---------------- final per-atom kernel (float32 output!) ----------------
__global__ __launch_bounds__(256) void k_final(const float* __restrict__ h, const float* __restrict__ x,
    const float* __restrict__ v, const float* __restrict__ Wf, const int* __restrict__ counts,
    const float* __restrict__ hsema, const float* __restrict__ comb, float* __restrict__ out){
  __shared__ float s_hsem[224];
  __shared__ float s_nsq[224];
  __shared__ float s_pv[256][3];
  __shared__ float s_u1[32], s_sp[32], s_un[32], s_g[32];
  __shared__ float s_sc;
  int a = blockIdx.x;
  int tid = threadIdx.x;
  int cnt = counts[a];
  float inv = 1.f / fmaxf((float)cnt, 1.f);
  if (tid < 224){
    s_hsem[tid] = hsema[(size_t)a*224 + tid];
    float cm0 = comb[((size_t)a*224 + tid)*3 + 0] * inv;
    float cm1 = comb[((size_t)a*224 + tid)*3 + 1] * inv;
    float cm2 = comb[((size_t)a*224 + tid)*3 + 2] * inv;
    s_nsq[tid] = cm0*cm0 + cm1*cm1 + cm2*cm2;
    float wv = Wf[OFF_WVMIX + tid];
    s_pv[tid][0] = wv * cm0; s_pv[tid][1] = wv * cm1; s_pv[tid][2] = wv * cm2;
  } else {
    s_pv[tid][0] = 0.f; s_pv[tid][1] = 0.f; s_pv[tid][2] = 0.f;
  }
  __syncthreads();
  #pragma unroll
  for (int st = 128; st >= 1; st >>= 1){
    if (tid < st){
      s_pv[tid][0] += s_pv[tid + st][0];
      s_pv[tid][1] += s_pv[tid + st][1];
      s_pv[tid][2] += s_pv[tid + st][2];
    }
    __syncthreads();
  }
  if (tid < 32){
    float u = Wf[OFF_BP1 + tid];
    for (int c = 0; c < 224; ++c) u += s_nsq[c] * Wf[OFF_WP1 + c * 32 + tid];
    s_u1[tid] = siluf(u);
  }
  __syncthreads();
  if (tid < 32){
    float u = Wf[OFF_BP2 + tid];
    #pragma unroll
    for (int k = 0; k < 32; ++k) u += s_u1[k] * Wf[OFF_WP2 + k * 32 + tid];
    s_sp[tid] = siluf(u);
  }
  __syncthreads();
  if (tid < 32){
    float u = Wf[OFF_BN1 + tid];
    #pragma unroll
    for (int k = 0; k < 32; ++k) u += h[a*32+k] * Wf[OFF_WN1 + k * 32 + tid];
    for (int c = 0; c < 224; ++c) u += s_hsem[c] * Wf[OFF_WN1 + (32 + c) * 32 + tid];
    #pragma unroll
    for (int k = 0; k < 32; ++k) u += s_sp[k] * Wf[OFF_WN1 + (256 + k) * 32 + tid];
    s_un[tid] = siluf(u);
  }
  __syncthreads();
  if (tid < 32){
    float u = Wf[OFF_BN2 + tid];
    #pragma unroll
    for (int k = 0; k < 32; ++k) u += s_un[k] * Wf[OFF_WN2 + k * 32 + tid];
    out[a*32+tid] = h[a*32+tid] + siluf(u);
    float g = Wf[OFF_BV1 + tid];
    #pragma unroll
    for (int k = 0; k < 32; ++k) g += h[a*32+k] * Wf[OFF_WV1 + k * 32 + tid];
    s_g[tid] = siluf(g);
  }
  __syncthreads();
  if (tid == 0){
    float z = 0.f;
    #pragma unroll
    for (int k = 0; k < 32; ++k) z += s_g[k] * Wf[OFF_WV2 + k];
    s_sc = 2.f / (1.f + __expf(-z));
  }
  __syncthreads();
  if (tid < 3){
    float dv = s_pv[0][tid];
    float vup = s_sc * v[a*3+tid] + dv;
    float xup = x[a*3+tid] + vup;
    out[N_ATOMS*32 + a*3 + tid] = xup;
    out[N_ATOMS*32 + N_ATOMS*3 + a*3 + tid] = vup;
  }
}

// ---------------- workspace layout ----------------
static constexpr size_t al256(size_t x){ return (x + 255) & ~(size_t)255; }
static constexpr size_t WS_FLAGS   = 0;
static constexpr size_t WS_COUNTS  = al256(WS_FLAGS + 8);
static constexpr size_t WS_SEGMAXE = al256(WS_COUNTS + (size_t)N_ATOMS * 4);
static constexpr size_t WS_SEGSUM  = al256(WS_SEGMAXE + (size_t)N_ATOMS * 7 * 4);
static constexpr size_t WS_AGG     = al256(WS_SEGSUM + (size_t)N_ATOMS * 7 * 4);
static constexpr size_t WS_INVSUM  = al256(WS_AGG + (size_t)N_ATOMS * 7 * 4);
static constexpr size_t WS_INVAGG  = al256(WS_INVSUM + (size_t)N_ATOMS * 7 * 4);
static constexpr size_t WS_PLI     = al256(WS_INVAGG + (size_t)N_ATOMS * 7 * 4);
static constexpr size_t WS_HF      = al256(WS_PLI + (size_t)2 * P_PAIRS * 4);
static constexpr size_t WS_XF      = al256(WS_HF + (size_t)N_ATOMS * 32 * 4);
static constexpr size_t WS_VF      = al256(WS_XF + (size_t)N_ATOMS * 3 * 4);
static constexpr size_t WS_WF      = al256(WS_VF + (size_t)N_ATOMS * 3 * 4);
static constexpr size_t WS_WX      = al256(WS_WF + (size_t)WF_TOTAL * 4);
static constexpr size_t WS_EDGE    = al256(WS_WX + (size_t)224 * 224 * 4);
static constexpr size_t WS_LOGITS  = al256(WS_EDGE + (size_t)P_PAIRS * 32 * 2);
static constexpr size_t WS_DIR     = al256(WS_LOGITS + (size_t)P_PAIRS * 7 * 4);
static constexpr size_t WS_EBUF    = al256(WS_DIR + (size_t)P_PAIRS * 3 * 4);
static constexpr size_t WS_HSEMA   = al256(WS_EBUF + (size_t)P_PAIRS * 7 * 4);
static constexpr size_t WS_COMB    = al256(WS_HSEMA + (size_t)N_ATOMS * 224 * 4);
static constexpr size_t WS_END     = WS_COMB + (size_t)N_ATOMS * 224 * 3 * 4;

extern "C" void kernel_launch(void* const* d_in, const int* in_sizes, int n_in,
                              void* d_out, int out_size, void* d_ws, size_t ws_size,
                              hipStream_t stream){
  static const int EXP_SIZES[25] = {
    320000, 30000, 30000, 320000,
    3200, 50, 3680, 32, 1024, 32,
    224, 7,
    9216, 32, 1024, 32,
    7168, 32, 1024, 32,
    1024, 32, 32,
    50176, 224
  };
  if (n_in != 25){
    k_code<<<1, 64, 0, stream>>>((float*)d_out, 5000.f + 100.f * (float)n_in);
    return;
  }
  for (int i = 0; i < 25; ++i){
    if (in_sizes[i] != EXP_SIZES[i]){
      k_code<<<1, 64, 0, stream>>>((float*)d_out, 10000.f + 100.f * (float)i);
      return;
    }
  }
  if (out_size != 380000 || ws_size < WS_END){
    k_code<<<1, 64, 0, stream>>>((float*)d_out, 14000.f);
    return;
  }

  char* ws = (char*)d_ws;
  int*   flags   = (int*)(ws + WS_FLAGS);
  int*   counts  = (int*)(ws + WS_COUNTS);
  u32*   segmaxe = (u32*)(ws + WS_SEGMAXE);
  float* segsum  = (float*)(ws + WS_SEGSUM);
  float* aggsum  = (float*)(ws + WS_AGG);
  float* invsum  = (float*)(ws + WS_INVSUM);
  float* invagg  = (float*)(ws + WS_INVAGG);
  int*   pli     = (int*)(ws + WS_PLI);
  float* hf      = (float*)(ws + WS_HF);
  float* xf      = (float*)(ws + WS_XF);
  float* vf      = (float*)(ws + WS_VF);
  float* Wf      = (float*)(ws + WS_WF);
  float* Wx      = (float*)(ws + WS_WX);
  u16*   edge    = (u16*)(ws + WS_EDGE);
  float* logits  = (float*)(ws + WS_LOGITS);
  float* dir     = (float*)(ws + WS_DIR);
  float* ebuf    = (float*)(ws + WS_EBUF);
  float* hsema   = (float*)(ws + WS_HSEMA);
  float* comb    = (float*)(ws + WS_COMB);

  hipMemsetAsync(counts, 0, (size_t)N_ATOMS * 4, stream);
  hipMemsetAsync(segmaxe, 0, (size_t)N_ATOMS * 7 * 4, stream);
  hipMemsetAsync(segsum, 0, (size_t)N_ATOMS * 7 * 4, stream);
  hipMemsetAsync(aggsum, 0, (size_t)N_ATOMS * 7 * 4, stream);
  hipMemsetAsync(hsema, 0, (size_t)N_ATOMS * 224 * 4, stream);
  hipMemsetAsync(comb, 0, (size_t)N_ATOMS * 224 * 3 * 4, stream);
  k_detect<<<1, 64, 0, stream>>>((const u32*)d_in[0], (const u32*)d_in[3], flags);
  k_norm<<<(700000 + 255) / 256, 256, 0, stream>>>(d_in[0], d_in[1], d_in[2], d_in[3],
                                                   flags, hf, xf, vf, pli);
  k_convert<<<(WF_TOTAL + 255) / 256, 256, 0, stream>>>(
      d_in[4],  d_in[5],  d_in[6],  d_in[7],  d_in[8],  d_in[9],  d_in[10], d_in[11],
      d_in[12], d_in[13], d_in[14], d_in[15], d_in[16], d_in[17], d_in[18], d_in[19],
      d_in[20], d_in[21], d_in[22], d_in[24], flags, Wf);
  k_wx<<<(224 * 224 + 255) / 256, 256, 0, stream>>>(d_in[23], flags, Wx);
  k_pair<<<P_PAIRS / 256, 256, 0, stream>>>(hf, xf, pli, Wf, edge, logits, dir);
  k_hist<<<P_PAIRS / 256, 256, 0, stream>>>(pli, counts);
  k_gmax<<<P_PAIRS / 256, 256, 0, stream>>>(pli, logits, segmaxe);
  k_gsum<<<P_PAIRS / 256, 256, 0, stream>>>(pli, logits, segmaxe, ebuf, segsum);
  k_inv<<<(N_ATOMS * 7 + 255) / 256, 256, 0, stream>>>(segsum, invsum);
  k_gagg<<<P_PAIRS / 256, 256, 0, stream>>>(pli, ebuf, invsum, aggsum);
  k_inv2<<<(N_ATOMS * 7 + 255) / 256, 256, 0, stream>>>(aggsum, counts, invagg);
  k_xmix2<<<P_PAIRS / 128, 256, 0, stream>>>(pli, edge, ebuf, invsum, invagg, dir, Wx, hsema, comb);
  k_final<<<N_ATOMS, 256, 0, stream>>>(hf, xf, vf, Wf, counts, hsema, comb, (float*)d_out);
}

// Round 8
// 531.555 us; speedup vs baseline: 3.3380x; 3.3380x over previous
//
#include <hip/hip_runtime.h>

typedef unsigned short u16;
typedef unsigned int u32;
typedef __attribute__((ext_vector_type(8))) short short8;
typedef __attribute__((ext_vector_type(4))) float floatx4;

#define P_PAIRS 160000
#define N_ATOMS 10000

#define OFF_WMLP  0
#define OFF_BMLP  3200
#define OFF_WE1   3250
#define OFF_BE1   6930
#define OFF_WE2   6962
#define OFF_BE2   7986
#define OFF_WATT  8018
#define OFF_BATT  8242
#define OFF_WN1   8249
#define OFF_BN1   17465
#define OFF_WN2   17497
#define OFF_BN2   18521
#define OFF_WP1   18553
#define OFF_BP1   25721
#define OFF_WP2   25753
#define OFF_BP2   26777
#define OFF_WV1   26809
#define OFF_BV1   27833
#define OFF_WV2   27865
#define OFF_WVMIX 27897
#define WF_TOTAL  28121

__device__ __forceinline__ float b2f(u16 u){ return __uint_as_float(((u32)u) << 16); }
__device__ __forceinline__ u16 f2b(float f){
  u32 u = __float_as_uint(f);
  u32 r = (u + 0x7FFFu + ((u >> 16) & 1u)) >> 16;
  return (u16)r;
}
__device__ __forceinline__ float siluf(float v){ return v / (1.f + __expf(-v)); }
__device__ __forceinline__ float ldw(const void* p, int o, int bf){
  return bf ? b2f(((const u16*)p)[o]) : ((const float*)p)[o];
}

__global__ void k_code(float* out, float code){
  if (threadIdx.x == 0 && blockIdx.x == 0) out[0] = code;
}

// ---------------- dtype detection ----------------
__global__ void k_detect(const u32* __restrict__ hw, const u32* __restrict__ plw,
                         int* __restrict__ flags){
  if (threadIdx.x == 0 && blockIdx.x == 0){
    int bf = 0;
    for (int k = 0; k < 64; ++k){
      u32 e = (hw[k] >> 7) & 0xFFu;
      if (e >= 100u && e <= 140u) bf++;
    }
    flags[0] = (bf >= 48) ? 1 : 0;
    int z = 0;
    for (int k = 0; k < 64; ++k) if (plw[2*k+1] == 0u) z++;
    flags[1] = (z >= 60) ? 1 : 0;
  }
}

// ---------------- input normalization ----------------
__global__ void k_norm(const void* __restrict__ h_raw, const void* __restrict__ x_raw,
                       const void* __restrict__ v_raw, const void* __restrict__ pl_raw,
                       const int* __restrict__ flags, float* __restrict__ hf,
                       float* __restrict__ xf, float* __restrict__ vf, int* __restrict__ pli){
  int t = blockIdx.x * 256 + threadIdx.x;
  int bf = flags[0], i64 = flags[1];
  if (t < 320000){
    hf[t] = ldw(h_raw, t, bf);
  } else if (t < 350000){
    int i = t - 320000;
    xf[i] = ldw(x_raw, i, bf);
  } else if (t < 380000){
    int i = t - 350000;
    vf[i] = ldw(v_raw, i, bf);
  } else if (t < 700000){
    int k = t - 380000;
    const int* p32 = (const int*)pl_raw;
    pli[k] = i64 ? p32[2*(size_t)k] : p32[k];
  }
}

// ---------------- weight conversion -> fp32 ----------------
__global__ void k_convert(const void* w_mlp, const void* b_mlp, const void* w_e1, const void* b_e1,
  const void* w_e2, const void* b_e2, const void* w_att, const void* b_att,
  const void* w_n1, const void* b_n1, const void* w_n2, const void* b_n2,
  const void* w_p1, const void* b_p1, const void* w_p2, const void* b_p2,
  const void* w_v1, const void* b_v1, const void* w_v2, const void* w_vmix,
  const int* __restrict__ flags, float* __restrict__ Wf){
  int t = blockIdx.x * 256 + threadIdx.x;
  if (t >= WF_TOTAL) return;
  int bf = flags[0];
  const void* src; int o;
  if      (t < 3200)  { src = w_mlp;  o = t; }
  else if (t < 3250)  { src = b_mlp;  o = t - 3200; }
  else if (t < 6930)  { src = w_e1;   o = t - 3250; }
  else if (t < 6962)  { src = b_e1;   o = t - 6930; }
  else if (t < 7986)  { src = w_e2;   o = t - 6962; }
  else if (t < 8018)  { src = b_e2;   o = t - 7986; }
  else if (t < 8242)  { src = w_att;  o = t - 8018; }
  else if (t < 8249)  { src = b_att;  o = t - 8242; }
  else if (t < 17465) { src = w_n1;   o = t - 8249; }
  else if (t < 17497) { src = b_n1;   o = t - 17465; }
  else if (t < 18521) { src = w_n2;   o = t - 17497; }
  else if (t < 18553) { src = b_n2;   o = t - 18521; }
  else if (t < 25721) { src = w_p1;   o = t - 18553; }
  else if (t < 25753) { src = b_p1;   o = t - 25721; }
  else if (t < 26777) { src = w_p2;   o = t - 25753; }
  else if (t < 26809) { src = b_p2;   o = t - 26777; }
  else if (t < 27833) { src = w_v1;   o = t - 26809; }
  else if (t < 27865) { src = b_v1;   o = t - 27833; }
  else if (t < 27897) { src = w_v2;   o = t - 27865; }
  else                { src = w_vmix; o = t - 27897; }
  Wf[t] = ldw(src, o, bf);
}

// wT[n][k] = w_xmix[k][n] as bf16 (B^T operand for MFMA)
__global__ void k_transpose(const void* __restrict__ wx, const int* __restrict__ flags,
                            u16* __restrict__ wT){
  int t = blockIdx.x * 256 + threadIdx.x;
  if (t >= 224 * 224) return;
  int n = t / 224, k = t - n * 224;
  wT[t] = f2b(ldw(wx, k * 224 + n, flags[0]));
}

// ---------------- per-pair edge model ----------------
__global__ __launch_bounds__(256) void k_pair(const float* __restrict__ h, const float* __restrict__ x,
    const int* __restrict__ pl, const float* __restrict__ Wf,
    u16* __restrict__ edge, float* __restrict__ logits, float* __restrict__ dir){
  int tid = threadIdx.x;
  int p = blockIdx.x * 256 + tid;
  int i = pl[p], j = pl[P_PAIRS + p];
  const float* hi = h + i * 32;
  const float* hj = h + j * 32;
  float r0 = x[j*3+0] - x[i*3+0];
  float r1 = x[j*3+1] - x[i*3+1];
  float r2 = x[j*3+2] - x[i*3+2];
  float d = sqrtf(r0*r0 + r1*r1 + r2*r2);
  float rinv = 1.f / (d + 1e-5f);
  dir[p*3+0] = r0*rinv; dir[p*3+1] = r1*rinv; dir[p*3+2] = r2*rinv;

  float filt[50];
  #pragma unroll
  for (int o = 0; o < 50; ++o) filt[o] = Wf[OFF_BMLP + o];
  for (int k = 0; k < 64; ++k){
    float hk = (k < 32) ? hi[k] : hj[k - 32];
    const float* wr = Wf + OFF_WMLP + k * 50;
    #pragma unroll
    for (int o = 0; o < 50; ++o) filt[o] += hk * wr[o];
  }
  #pragma unroll
  for (int o = 0; o < 50; ++o){
    float c = (float)o * (5.0f / 49.0f);
    float dd = d - c;
    filt[o] *= __expf(-10.0f * dd * dd);
  }
  float u[32];
  #pragma unroll
  for (int o = 0; o < 32; ++o) u[o] = Wf[OFF_BE1 + o];
  for (int k = 0; k < 64; ++k){
    float ek = (k < 32) ? hi[k] : hj[k - 32];
    const float* wr = Wf + OFF_WE1 + k * 32;
    #pragma unroll
    for (int o = 0; o < 32; ++o) u[o] += ek * wr[o];
  }
  #pragma unroll
  for (int kk = 0; kk < 50; ++kk){
    const float* wr = Wf + OFF_WE1 + (64 + kk) * 32;
    #pragma unroll
    for (int o = 0; o < 32; ++o) u[o] += filt[kk] * wr[o];
  }
  {
    const float* wr = Wf + OFF_WE1 + 114 * 32;
    #pragma unroll
    for (int o = 0; o < 32; ++o) u[o] += d * wr[o];
  }
  #pragma unroll
  for (int o = 0; o < 32; ++o) u[o] = siluf(u[o]);
  float eg[32];
  #pragma unroll
  for (int o = 0; o < 32; ++o) eg[o] = Wf[OFF_BE2 + o];
  #pragma unroll
  for (int k = 0; k < 32; ++k){
    const float* wr = Wf + OFF_WE2 + k * 32;
    #pragma unroll
    for (int o = 0; o < 32; ++o) eg[o] += u[k] * wr[o];
  }
  {
    u32 st[16];
    #pragma unroll
    for (int o = 0; o < 16; ++o)
      st[o] = (u32)f2b(eg[2*o]) | ((u32)f2b(eg[2*o+1]) << 16);
    #pragma unroll
    for (int q = 0; q < 4; ++q){
      uint4 vv; vv.x = st[4*q]; vv.y = st[4*q+1]; vv.z = st[4*q+2]; vv.w = st[4*q+3];
      *(uint4*)(edge + (size_t)p * 32 + q * 8) = vv;
    }
  }
  float lg[7];
  #pragma unroll
  for (int o = 0; o < 7; ++o) lg[o] = Wf[OFF_BATT + o];
  #pragma unroll
  for (int k = 0; k < 32; ++k){
    const float* wr = Wf + OFF_WATT + k * 7;
    #pragma unroll
    for (int o = 0; o < 7; ++o) lg[o] += eg[k] * wr[o];
  }
  #pragma unroll
  for (int o = 0; o < 7; ++o){
    float vv = lg[o];
    float cl = vv > 0.f ? vv : 2.f * expm1f(0.5f * vv);
    logits[p*7+o] = cl;
  }
}

// ---------------- counting sort ----------------
__global__ void k_hist(const int* __restrict__ pl, int* __restrict__ counts){
  int p = blockIdx.x * 256 + threadIdx.x;
  atomicAdd(&counts[pl[p]], 1);
}

__global__ void k_scan(const int* __restrict__ counts, int* __restrict__ offs, int* __restrict__ cursor){
  __shared__ int part[256];
  int t = threadIdx.x;
  int sum = 0;
  for (int k = 0; k < 40; ++k){
    int idx = t * 40 + k;
    if (idx < N_ATOMS) sum += counts[idx];
  }
  part[t] = sum;
  __syncthreads();
  if (t == 0){
    int run = 0;
    for (int q = 0; q < 256; ++q){ int tmp = part[q]; part[q] = run; run += tmp; }
  }
  __syncthreads();
  int run = part[t];
  for (int k = 0; k < 40; ++k){
    int idx = t * 40 + k;
    if (idx < N_ATOMS){ offs[idx] = run; cursor[idx] = run; run += counts[idx]; }
  }
  if (t == 0) offs[N_ATOMS] = P_PAIRS;
}

__global__ void k_scatter(const int* __restrict__ pl, int* __restrict__ cursor, int* __restrict__ perm){
  int p = blockIdx.x * 256 + threadIdx.x;
  int i = pl[p];
  int pos = atomicAdd(&cursor[i], 1);
  perm[pos] = p;
}

// ---------------- segment softmax (wave per atom, sorted outputs) ----------
__global__ __launch_bounds__(256) void k_att(const int* __restrict__ perm, const int* __restrict__ offs,
    const float* __restrict__ logits, const float* __restrict__ dir,
    float* __restrict__ atts, float* __restrict__ dirs, int* __restrict__ aid){
  int a = blockIdx.x * 4 + (threadIdx.x >> 6);   // N = 2500*4
  int lane = threadIdx.x & 63;
  int off = offs[a], end = offs[a+1];
  float m[7];
  #pragma unroll
  for (int hh = 0; hh < 7; ++hh) m[hh] = -1e30f;
  for (int s = off + lane; s < end; s += 64){
    int p = perm[s];
    #pragma unroll
    for (int hh = 0; hh < 7; ++hh) m[hh] = fmaxf(m[hh], logits[p*7+hh]);
  }
  #pragma unroll
  for (int hh = 0; hh < 7; ++hh){
    float v = m[hh];
    #pragma unroll
    for (int msk = 32; msk >= 1; msk >>= 1) v = fmaxf(v, __shfl_xor(v, msk));
    m[hh] = v;
  }
  float sm[7] = {0,0,0,0,0,0,0};
  for (int s = off + lane; s < end; s += 64){
    int p = perm[s];
    #pragma unroll
    for (int hh = 0; hh < 7; ++hh){
      float e = __expf(logits[p*7+hh] - m[hh]);
      sm[hh] += e;
      atts[s*7+hh] = e;
    }
    dirs[s*3+0] = dir[p*3+0]; dirs[s*3+1] = dir[p*3+1]; dirs[s*3+2] = dir[p*3+2];
    aid[s] = a;
  }
  #pragma unroll
  for (int hh = 0; hh < 7; ++hh){
    float v = sm[hh];
    #pragma unroll
    for (int msk = 32; msk >= 1; msk >>= 1) v += __shfl_xor(v, msk);
    sm[hh] = 1.f / v;
  }
  for (int s = off + lane; s < end; s += 64){
    #pragma unroll
    for (int hh = 0; hh < 7; ++hh) atts[s*7+hh] *= sm[hh];
  }
}

// ---------------- MFMA GEMM: x_mixed = tanh((edge*att) @ w_xmix), seg comb --
// LDS map: As bf16[128][40] @0 (10240) | Bs bf16[224][40] @10240 (->28160)
//          eL u16[128][32] @28160 (->36352) | aL f32[128][7] @36352 (->39936)
//          phase2: xt bf16[128][232] @0 (59392)
//          persistent: dL f32[128][3] @59392 (->60928) | idL i32[128] @60928 (->61440)
#define GLDS_BS   10240
#define GLDS_EL   28160
#define GLDS_AL   36352
#define GLDS_DL   59392
#define GLDS_ID   60928
#define GLDS_TOT  61440

__global__ __launch_bounds__(256) void k_gemm2(const int* __restrict__ perm,
    const int* __restrict__ aid, const u16* __restrict__ edge,
    const float* __restrict__ atts, const float* __restrict__ dirs,
    const u16* __restrict__ BT, float* __restrict__ comb){
  __shared__ __attribute__((aligned(16))) char smem[GLDS_TOT];
  u16*   As = (u16*)smem;
  u16*   Bs = (u16*)(smem + GLDS_BS);
  u16*   eL = (u16*)(smem + GLDS_EL);
  float* aL = (float*)(smem + GLDS_AL);
  float* dL = (float*)(smem + GLDS_DL);
  int*  idL = (int*)(smem + GLDS_ID);
  int tid = threadIdx.x;
  int wave = tid >> 6, lane = tid & 63, l15 = lane & 15, quad = lane >> 4;
  int row0 = blockIdx.x * 128;                   // 1250*128 = P

  if (tid < 128){
    idL[tid] = aid[row0 + tid];
    dL[tid*3+0] = dirs[(row0+tid)*3+0];
    dL[tid*3+1] = dirs[(row0+tid)*3+1];
    dL[tid*3+2] = dirs[(row0+tid)*3+2];
  }
  for (int e = tid; e < 896; e += 256) aL[e] = atts[(size_t)row0*7 + e];
  for (int e = tid; e < 512; e += 256){
    int r = e >> 2, q = e & 3;
    int p = perm[row0 + r];
    *(uint4*)(eL + r*32 + q*8) = *(const uint4*)(edge + (size_t)p*32 + q*8);
  }
  floatx4 acc[2][14];
  #pragma unroll
  for (int mt = 0; mt < 2; ++mt)
    #pragma unroll
    for (int nt = 0; nt < 14; ++nt)
      acc[mt][nt] = (floatx4){0.f, 0.f, 0.f, 0.f};
  __syncthreads();

  for (int kt = 0; kt < 7; ++kt){
    int kk = kt * 32;
    for (int e = tid; e < 896; e += 256){
      int r = e >> 2, q = e & 3;
      *(uint4*)(Bs + r*40 + q*8) = *(const uint4*)(BT + (size_t)r*224 + kk + q*8);
    }
    // As[r][c] = edge[r][(kk+c)/7] * att[r][(kk+c)%7], bf16 packed x2
    for (int e = tid; e < 2048; e += 256){
      int r = e >> 4, c2 = (e & 15) * 2;
      int kc = kk + c2;
      int f0 = kc / 7,  h0 = kc - f0 * 7;
      int kc1 = kc + 1;
      int f1 = kc1 / 7, h1 = kc1 - f1 * 7;
      float v0 = b2f(eL[r*32 + f0]) * aL[r*7 + h0];
      float v1 = b2f(eL[r*32 + f1]) * aL[r*7 + h1];
      ((u32*)As)[r*20 + (e & 15)] = (u32)f2b(v0) | ((u32)f2b(v1) << 16);
    }
    __syncthreads();
    short8 a0 = *(const short8*)(As + (wave*32 + l15)*40 + quad*8);
    short8 a1 = *(const short8*)(As + (wave*32 + 16 + l15)*40 + quad*8);
    #pragma unroll
    for (int nt = 0; nt < 14; ++nt){
      short8 b = *(const short8*)(Bs + (nt*16 + l15)*40 + quad*8);
      acc[0][nt] = __builtin_amdgcn_mfma_f32_16x16x32_bf16(a0, b, acc[0][nt], 0, 0, 0);
      acc[1][nt] = __builtin_amdgcn_mfma_f32_16x16x32_bf16(a1, b, acc[1][nt], 0, 0, 0);
    }
    __syncthreads();
  }
  // epilogue: tanh -> xt (aliases As/Bs/eL/aL)
  u16* xt = (u16*)smem;
  #pragma unroll
  for (int mt = 0; mt < 2; ++mt)
    #pragma unroll
    for (int nt = 0; nt < 14; ++nt)
      #pragma unroll
      for (int reg = 0; reg < 4; ++reg){
        int r = wave*32 + mt*16 + quad*4 + reg;
        int c = nt*16 + l15;
        float vv = acc[mt][nt][reg];
        vv = fminf(fmaxf(vv, -15.f), 15.f);
        float e2 = __expf(2.f * vv);
        xt[r*232 + c] = f2b((e2 - 1.f) / (e2 + 1.f));
      }
  __syncthreads();
  // segmented column reduction -> comb (idL ascending within block)
  if (tid < 224){
    int c = tid;
    int acur = idL[0];
    float s0 = 0.f, s1 = 0.f, s2 = 0.f;
    for (int r = 0; r < 128; ++r){
      int ar = idL[r];
      if (ar != acur){
        atomicAdd(&comb[((size_t)acur*224 + c)*3 + 0], s0);
        atomicAdd(&comb[((size_t)acur*224 + c)*3 + 1], s1);
        atomicAdd(&comb[((size_t)acur*224 + c)*3 + 2], s2);
        s0 = s1 = s2 = 0.f; acur = ar;
      }
      float xv = b2f(xt[r*232 + c]);
      s0 += dL[r*3+0] * xv;
      s1 += dL[r*3+1] * xv;
      s2 += dL[r*3+2] * xv;
    }
    atomicAdd(&comb[((size_t)acur*224 + c)*3 + 0], s0);
    atomicAdd(&comb[((size_t)acur*224 + c)*3 + 1], s1);
    atomicAdd(&comb[((size_t)acur*224 + c)*3 + 2], s2);
  }
}

// ---------------- final per-atom kernel (fp32 output) ----------------
__global__ __launch_bounds__(256) void k_final(const float* __restrict__ h, const float* __restrict__ x,
    const float* __restrict__ v, const float* __restrict__ Wf, const int* __restrict__ offs,
    const int* __restrict__ perm, const u16* __restrict__ edge, const float* __restrict__ atts,
    const float* __restrict__ comb, float* __restrict__ out){
  __shared__ float s_hsem[224];
  __shared__ float s_nsq[224];
  __shared__ float s_pv[256][3];
  __shared__ float s_u1[32], s_sp[32], s_un[32], s_g[32];
  __shared__ float s_sc;
  int a = blockIdx.x;
  int tid = threadIdx.x;
  int off = offs[a], end = offs[a+1];
  int cnt = end - off;
  float inv = 1.f / fmaxf((float)cnt, 1.f);
  if (tid < 224){
    int f = tid / 7, hh = tid - f * 7;
    float hsum = 0.f;
    for (int s = off; s < end; ++s){
      int p = perm[s];
      hsum += b2f(edge[(size_t)p*32 + f]) * atts[s*7 + hh];
    }
    s_hsem[tid] = hsum;
    float cm0 = comb[((size_t)a*224 + tid)*3 + 0] * inv;
    float cm1 = comb[((size_t)a*224 + tid)*3 + 1] * inv;
    float cm2 = comb[((size_t)a*224 + tid)*3 + 2] * inv;
    s_nsq[tid] = cm0*cm0 + cm1*cm1 + cm2*cm2;
    float wv = Wf[OFF_WVMIX + tid];
    s_pv[tid][0] = wv * cm0; s_pv[tid][1] = wv * cm1; s_pv[tid][2] = wv * cm2;
  } else {
    s_pv[tid][0] = 0.f; s_pv[tid][1] = 0.f; s_pv[tid][2] = 0.f;
  }
  __syncthreads();
  #pragma unroll
  for (int st = 128; st >= 1; st >>= 1){
    if (tid < st){
      s_pv[tid][0] += s_pv[tid + st][0];
      s_pv[tid][1] += s_pv[tid + st][1];
      s_pv[tid][2] += s_pv[tid + st][2];
    }
    __syncthreads();
  }
  if (tid < 32){
    float u = Wf[OFF_BP1 + tid];
    for (int c = 0; c < 224; ++c) u += s_nsq[c] * Wf[OFF_WP1 + c * 32 + tid];
    s_u1[tid] = siluf(u);
  }
  __syncthreads();
  if (tid < 32){
    float u = Wf[OFF_BP2 + tid];
    #pragma unroll
    for (int k = 0; k < 32; ++k) u += s_u1[k] * Wf[OFF_WP2 + k * 32 + tid];
    s_sp[tid] = siluf(u);
  }
  __syncthreads();
  if (tid < 32){
    float u = Wf[OFF_BN1 + tid];
    #pragma unroll
    for (int k = 0; k < 32; ++k) u += h[a*32+k] * Wf[OFF_WN1 + k * 32 + tid];
    for (int c = 0; c < 224; ++c) u += s_hsem[c] * Wf[OFF_WN1 + (32 + c) * 32 + tid];
    #pragma unroll
    for (int k = 0; k < 32; ++k) u += s_sp[k] * Wf[OFF_WN1 + (256 + k) * 32 + tid];
    s_un[tid] = siluf(u);
  }
  __syncthreads();
  if (tid < 32){
    float u = Wf[OFF_BN2 + tid];
    #pragma unroll
    for (int k = 0; k < 32; ++k) u += s_un[k] * Wf[OFF_WN2 + k * 32 + tid];
    out[a*32+tid] = h[a*32+tid] + siluf(u);
    float g = Wf[OFF_BV1 + tid];
    #pragma unroll
    for (int k = 0; k < 32; ++k) g += h[a*32+k] * Wf[OFF_WV1 + k * 32 + tid];
    s_g[tid] = siluf(g);
  }
  __syncthreads();
  if (tid == 0){
    float z = 0.f;
    #pragma unroll
    for (int k = 0; k < 32; ++k) z += s_g[k] * Wf[OFF_WV2 + k];
    s_sc = 2.f / (1.f + __expf(-z));
  }
  __syncthreads();
  if (tid < 3){
    float dv = s_pv[0][tid];
    float vup = s_sc * v[a*3+tid] + dv;
    float xup = x[a*3+tid] + vup;
    out[N_ATOMS*32 + a*3 + tid] = xup;
    out[N_ATOMS*32 + N_ATOMS*3 + a*3 + tid] = vup;
  }
}

// ---------------- workspace layout (~57 MB) ----------------
static constexpr size_t al256(size_t x){ return (x + 255) & ~(size_t)255; }
static constexpr size_t WS_FLAGS   = 0;
static constexpr size_t WS_COUNTS  = al256(WS_FLAGS + 8);
static constexpr size_t WS_OFFSETS = al256(WS_COUNTS + (size_t)N_ATOMS * 4);
static constexpr size_t WS_CURSOR  = al256(WS_OFFSETS + (size_t)(N_ATOMS + 1) * 4);
static constexpr size_t WS_PERM    = al256(WS_CURSOR + (size_t)N_ATOMS * 4);
static constexpr size_t WS_AID     = al256(WS_PERM + (size_t)P_PAIRS * 4);
static constexpr size_t WS_PLI     = al256(WS_AID + (size_t)P_PAIRS * 4);
static constexpr size_t WS_HF      = al256(WS_PLI + (size_t)2 * P_PAIRS * 4);
static constexpr size_t WS_XF      = al256(WS_HF + (size_t)N_ATOMS * 32 * 4);
static constexpr size_t WS_VF      = al256(WS_XF + (size_t)N_ATOMS * 3 * 4);
static constexpr size_t WS_WF      = al256(WS_VF + (size_t)N_ATOMS * 3 * 4);
static constexpr size_t WS_WT      = al256(WS_WF + (size_t)WF_TOTAL * 4);
static constexpr size_t WS_EDGE    = al256(WS_WT + (size_t)224 * 224 * 2);
static constexpr size_t WS_LOGITS  = al256(WS_EDGE + (size_t)P_PAIRS * 32 * 2);
static constexpr size_t WS_DIR     = al256(WS_LOGITS + (size_t)P_PAIRS * 7 * 4);
static constexpr size_t WS_ATTS    = al256(WS_DIR + (size_t)P_PAIRS * 3 * 4);
static constexpr size_t WS_DIRS    = al256(WS_ATTS + (size_t)P_PAIRS * 7 * 4);
static constexpr size_t WS_COMB    = al256(WS_DIRS + (size_t)P_PAIRS * 3 * 4);
static constexpr size_t WS_END     = WS_COMB + (size_t)N_ATOMS * 224 * 3 * 4;

extern "C" void kernel_launch(void* const* d_in, const int* in_sizes, int n_in,
                              void* d_out, int out_size, void* d_ws, size_t ws_size,
                              hipStream_t stream){
  (void)in_sizes; (void)n_in;
  if (out_size != 380000 || ws_size < WS_END){
    k_code<<<1, 64, 0, stream>>>((float*)d_out, 14000.f);
    return;
  }
  char* ws = (char*)d_ws;
  int*   flags  = (int*)(ws + WS_FLAGS);
  int*   counts = (int*)(ws + WS_COUNTS);
  int*   offs   = (int*)(ws + WS_OFFSETS);
  int*   cursor = (int*)(ws + WS_CURSOR);
  int*   perm   = (int*)(ws + WS_PERM);
  int*   aid    = (int*)(ws + WS_AID);
  int*   pli    = (int*)(ws + WS_PLI);
  float* hf     = (float*)(ws + WS_HF);
  float* xf     = (float*)(ws + WS_XF);
  float* vf     = (float*)(ws + WS_VF);
  float* Wf     = (float*)(ws + WS_WF);
  u16*   wT     = (u16*)(ws + WS_WT);
  u16*   edge   = (u16*)(ws + WS_EDGE);
  float* logits = (float*)(ws + WS_LOGITS);
  float* dir    = (float*)(ws + WS_DIR);
  float* atts   = (float*)(ws + WS_ATTS);
  float* dirs   = (float*)(ws + WS_DIRS);
  float* comb   = (float*)(ws + WS_COMB);

  hipMemsetAsync(counts, 0, (size_t)N_ATOMS * 4, stream);
  hipMemsetAsync(comb, 0, (size_t)N_ATOMS * 224 * 3 * 4, stream);
  k_detect<<<1, 64, 0, stream>>>((const u32*)d_in[0], (const u32*)d_in[3], flags);
  k_norm<<<(700000 + 255) / 256, 256, 0, stream>>>(d_in[0], d_in[1], d_in[2], d_in[3],
                                                   flags, hf, xf, vf, pli);
  k_convert<<<(WF_TOTAL + 255) / 256, 256, 0, stream>>>(
      d_in[4],  d_in[5],  d_in[6],  d_in[7],  d_in[8],  d_in[9],  d_in[10], d_in[11],
      d_in[12], d_in[13], d_in[14], d_in[15], d_in[16], d_in[17], d_in[18], d_in[19],
      d_in[20], d_in[21], d_in[22], d_in[24], flags, Wf);
  k_transpose<<<(224 * 224 + 255) / 256, 256, 0, stream>>>(d_in[23], flags, wT);
  k_pair<<<P_PAIRS / 256, 256, 0, stream>>>(hf, xf, pli, Wf, edge, logits, dir);
  k_hist<<<P_PAIRS / 256, 256, 0, stream>>>(pli, counts);
  k_scan<<<1, 256, 0, stream>>>(counts, offs, cursor);
  k_scatter<<<P_PAIRS / 256, 256, 0, stream>>>(pli, cursor, perm);
  k_att<<<N_ATOMS / 4, 256, 0, stream>>>(perm, offs, logits, dir, atts, dirs, aid);
  k_gemm2<<<P_PAIRS / 128, 256, 0, stream>>>(perm, aid, edge, atts, dirs, wT, comb);
  k_final<<<N_ATOMS, 256, 0, stream>>>(hf, xf, vf, Wf, offs, perm, edge, atts, comb, (float*)d_out);
}

// Round 9
// 464.158 us; speedup vs baseline: 3.8226x; 1.1452x over previous
//
#include <hip/hip_runtime.h>

typedef unsigned short u16;
typedef unsigned int u32;
typedef __attribute__((ext_vector_type(8))) short short8;
typedef __attribute__((ext_vector_type(4))) float floatx4;

#define P_PAIRS 160000
#define N_ATOMS 10000

#define OFF_WMLP  0
#define OFF_BMLP  3200
#define OFF_WE1   3250
#define OFF_BE1   6930
#define OFF_WE2   6962
#define OFF_BE2   7986
#define OFF_WATT  8018
#define OFF_BATT  8242
#define OFF_WN1   8249
#define OFF_BN1   17465
#define OFF_WN2   17497
#define OFF_BN2   18521
#define OFF_WP1   18553
#define OFF_BP1   25721
#define OFF_WP2   25753
#define OFF_BP2   26777
#define OFF_WV1   26809
#define OFF_BV1   27833
#define OFF_WV2   27865
#define OFF_WVMIX 27897
#define WF_TOTAL  28121

__device__ __forceinline__ float b2f(u16 u){ return __uint_as_float(((u32)u) << 16); }
__device__ __forceinline__ u16 f2b(float f){
  u32 u = __float_as_uint(f);
  u32 r = (u + 0x7FFFu + ((u >> 16) & 1u)) >> 16;
  return (u16)r;
}
__device__ __forceinline__ float siluf(float v){ return v / (1.f + __expf(-v)); }
__device__ __forceinline__ float ldw(const void* p, int o, int bf){
  return bf ? b2f(((const u16*)p)[o]) : ((const float*)p)[o];
}

__global__ void k_code(float* out, float code){
  if (threadIdx.x == 0 && blockIdx.x == 0) out[0] = code;
}

// ---------------- dtype detection ----------------
__global__ void k_detect(const u32* __restrict__ hw, const u32* __restrict__ plw,
                         int* __restrict__ flags){
  if (threadIdx.x == 0 && blockIdx.x == 0){
    int bf = 0;
    for (int k = 0; k < 64; ++k){
      u32 e = (hw[k] >> 7) & 0xFFu;
      if (e >= 100u && e <= 140u) bf++;
    }
    flags[0] = (bf >= 48) ? 1 : 0;
    int z = 0;
    for (int k = 0; k < 64; ++k) if (plw[2*k+1] == 0u) z++;
    flags[1] = (z >= 60) ? 1 : 0;
  }
}

// ---------------- input normalization ----------------
__global__ void k_norm(const void* __restrict__ h_raw, const void* __restrict__ x_raw,
                       const void* __restrict__ v_raw, const void* __restrict__ pl_raw,
                       const int* __restrict__ flags, float* __restrict__ hf,
                       float* __restrict__ xf, float* __restrict__ vf, int* __restrict__ pli){
  int t = blockIdx.x * 256 + threadIdx.x;
  int bf = flags[0], i64 = flags[1];
  if (t < 320000){
    hf[t] = ldw(h_raw, t, bf);
  } else if (t < 350000){
    int i = t - 320000;
    xf[i] = ldw(x_raw, i, bf);
  } else if (t < 380000){
    int i = t - 350000;
    vf[i] = ldw(v_raw, i, bf);
  } else if (t < 700000){
    int k = t - 380000;
    const int* p32 = (const int*)pl_raw;
    pli[k] = i64 ? p32[2*(size_t)k] : p32[k];
  }
}

// ---------------- weight conversion -> fp32 ----------------
__global__ void k_convert(const void* w_mlp, const void* b_mlp, const void* w_e1, const void* b_e1,
  const void* w_e2, const void* b_e2, const void* w_att, const void* b_att,
  const void* w_n1, const void* b_n1, const void* w_n2, const void* b_n2,
  const void* w_p1, const void* b_p1, const void* w_p2, const void* b_p2,
  const void* w_v1, const void* b_v1, const void* w_v2, const void* w_vmix,
  const int* __restrict__ flags, float* __restrict__ Wf){
  int t = blockIdx.x * 256 + threadIdx.x;
  if (t >= WF_TOTAL) return;
  int bf = flags[0];
  const void* src; int o;
  if      (t < 3200)  { src = w_mlp;  o = t; }
  else if (t < 3250)  { src = b_mlp;  o = t - 3200; }
  else if (t < 6930)  { src = w_e1;   o = t - 3250; }
  else if (t < 6962)  { src = b_e1;   o = t - 6930; }
  else if (t < 7986)  { src = w_e2;   o = t - 6962; }
  else if (t < 8018)  { src = b_e2;   o = t - 7986; }
  else if (t < 8242)  { src = w_att;  o = t - 8018; }
  else if (t < 8249)  { src = b_att;  o = t - 8242; }
  else if (t < 17465) { src = w_n1;   o = t - 8249; }
  else if (t < 17497) { src = b_n1;   o = t - 17465; }
  else if (t < 18521) { src = w_n2;   o = t - 17497; }
  else if (t < 18553) { src = b_n2;   o = t - 18521; }
  else if (t < 25721) { src = w_p1;   o = t - 18553; }
  else if (t < 25753) { src = b_p1;   o = t - 25721; }
  else if (t < 26777) { src = w_p2;   o = t - 25753; }
  else if (t < 26809) { src = b_p2;   o = t - 26777; }
  else if (t < 27833) { src = w_v1;   o = t - 26809; }
  else if (t < 27865) { src = b_v1;   o = t - 27833; }
  else if (t < 27897) { src = w_v2;   o = t - 27865; }
  else                { src = w_vmix; o = t - 27897; }
  Wf[t] = ldw(src, o, bf);
}

// wT[n][k] = w_xmix[k][n] as bf16 (B^T operand for MFMA)
__global__ void k_transpose(const void* __restrict__ wx, const int* __restrict__ flags,
                            u16* __restrict__ wT){
  int t = blockIdx.x * 256 + threadIdx.x;
  if (t >= 224 * 224) return;
  int n = t / 224, k = t - n * 224;
  wT[t] = f2b(ldw(wx, k * 224 + n, flags[0]));
}

// ---------------- counting sort (runs before k_pair) ----------------
__global__ void k_hist(const int* __restrict__ pl, int* __restrict__ counts){
  int p = blockIdx.x * 256 + threadIdx.x;
  atomicAdd(&counts[pl[p]], 1);
}

__global__ void k_scan(const int* __restrict__ counts, int* __restrict__ offs, int* __restrict__ cursor){
  __shared__ int part[256];
  int t = threadIdx.x;
  int sum = 0;
  for (int k = 0; k < 40; ++k){
    int idx = t * 40 + k;
    if (idx < N_ATOMS) sum += counts[idx];
  }
  part[t] = sum;
  __syncthreads();
  if (t == 0){
    int run = 0;
    for (int q = 0; q < 256; ++q){ int tmp = part[q]; part[q] = run; run += tmp; }
  }
  __syncthreads();
  int run = part[t];
  for (int k = 0; k < 40; ++k){
    int idx = t * 40 + k;
    if (idx < N_ATOMS){ offs[idx] = run; cursor[idx] = run; run += counts[idx]; }
  }
  if (t == 0) offs[N_ATOMS] = P_PAIRS;
}

__global__ void k_scatter(const int* __restrict__ pl, int* __restrict__ cursor, int* __restrict__ perm){
  int p = blockIdx.x * 256 + threadIdx.x;
  int i = pl[p];
  int pos = atomicAdd(&cursor[i], 1);
  perm[pos] = p;
}

// ---------------- per-pair edge model (writes SORTED slots) ----------------
__global__ __launch_bounds__(256) void k_pair(const float* __restrict__ h, const float* __restrict__ x,
    const int* __restrict__ pl, const int* __restrict__ perm, const float* __restrict__ Wf,
    u16* __restrict__ edge, float* __restrict__ logits, float* __restrict__ dirs){
  int tid = threadIdx.x;
  int s = blockIdx.x * 256 + tid;            // sorted slot
  int p = perm[s];
  int i = pl[p], j = pl[P_PAIRS + p];
  const float* hi = h + i * 32;
  const float* hj = h + j * 32;
  float r0 = x[j*3+0] - x[i*3+0];
  float r1 = x[j*3+1] - x[i*3+1];
  float r2 = x[j*3+2] - x[i*3+2];
  float d = sqrtf(r0*r0 + r1*r1 + r2*r2);
  float rinv = 1.f / (d + 1e-5f);
  dirs[s*3+0] = r0*rinv; dirs[s*3+1] = r1*rinv; dirs[s*3+2] = r2*rinv;

  float filt[50];
  #pragma unroll
  for (int o = 0; o < 50; ++o) filt[o] = Wf[OFF_BMLP + o];
  for (int k = 0; k < 64; ++k){
    float hk = (k < 32) ? hi[k] : hj[k - 32];
    const float* wr = Wf + OFF_WMLP + k * 50;
    #pragma unroll
    for (int o = 0; o < 50; ++o) filt[o] += hk * wr[o];
  }
  #pragma unroll
  for (int o = 0; o < 50; ++o){
    float c = (float)o * (5.0f / 49.0f);
    float dd = d - c;
    filt[o] *= __expf(-10.0f * dd * dd);
  }
  float u[32];
  #pragma unroll
  for (int o = 0; o < 32; ++o) u[o] = Wf[OFF_BE1 + o];
  for (int k = 0; k < 64; ++k){
    float ek = (k < 32) ? hi[k] : hj[k - 32];
    const float* wr = Wf + OFF_WE1 + k * 32;
    #pragma unroll
    for (int o = 0; o < 32; ++o) u[o] += ek * wr[o];
  }
  #pragma unroll
  for (int kk = 0; kk < 50; ++kk){
    const float* wr = Wf + OFF_WE1 + (64 + kk) * 32;
    #pragma unroll
    for (int o = 0; o < 32; ++o) u[o] += filt[kk] * wr[o];
  }
  {
    const float* wr = Wf + OFF_WE1 + 114 * 32;
    #pragma unroll
    for (int o = 0; o < 32; ++o) u[o] += d * wr[o];
  }
  #pragma unroll
  for (int o = 0; o < 32; ++o) u[o] = siluf(u[o]);
  float eg[32];
  #pragma unroll
  for (int o = 0; o < 32; ++o) eg[o] = Wf[OFF_BE2 + o];
  #pragma unroll
  for (int k = 0; k < 32; ++k){
    const float* wr = Wf + OFF_WE2 + k * 32;
    #pragma unroll
    for (int o = 0; o < 32; ++o) eg[o] += u[k] * wr[o];
  }
  {
    u32 st[16];
    #pragma unroll
    for (int o = 0; o < 16; ++o)
      st[o] = (u32)f2b(eg[2*o]) | ((u32)f2b(eg[2*o+1]) << 16);
    #pragma unroll
    for (int q = 0; q < 4; ++q){
      uint4 vv; vv.x = st[4*q]; vv.y = st[4*q+1]; vv.z = st[4*q+2]; vv.w = st[4*q+3];
      *(uint4*)(edge + (size_t)s * 32 + q * 8) = vv;
    }
  }
  float lg[7];
  #pragma unroll
  for (int o = 0; o < 7; ++o) lg[o] = Wf[OFF_BATT + o];
  #pragma unroll
  for (int k = 0; k < 32; ++k){
    const float* wr = Wf + OFF_WATT + k * 7;
    #pragma unroll
    for (int o = 0; o < 7; ++o) lg[o] += eg[k] * wr[o];
  }
  #pragma unroll
  for (int o = 0; o < 7; ++o){
    float vv = lg[o];
    float cl = vv > 0.f ? vv : 2.f * expm1f(0.5f * vv);
    logits[s*7+o] = cl;
  }
}

// ---------------- segment softmax (wave per atom, all contiguous) ----------
__global__ __launch_bounds__(256) void k_att(const int* __restrict__ offs,
    const float* __restrict__ logits, float* __restrict__ atts, int* __restrict__ aid){
  int a = blockIdx.x * 4 + (threadIdx.x >> 6);   // N = 2500*4
  int lane = threadIdx.x & 63;
  int off = offs[a], end = offs[a+1];
  float m[7];
  #pragma unroll
  for (int hh = 0; hh < 7; ++hh) m[hh] = -1e30f;
  for (int s = off + lane; s < end; s += 64){
    #pragma unroll
    for (int hh = 0; hh < 7; ++hh) m[hh] = fmaxf(m[hh], logits[s*7+hh]);
  }
  #pragma unroll
  for (int hh = 0; hh < 7; ++hh){
    float v = m[hh];
    #pragma unroll
    for (int msk = 32; msk >= 1; msk >>= 1) v = fmaxf(v, __shfl_xor(v, msk));
    m[hh] = v;
  }
  float sm[7] = {0,0,0,0,0,0,0};
  for (int s = off + lane; s < end; s += 64){
    #pragma unroll
    for (int hh = 0; hh < 7; ++hh){
      float e = __expf(logits[s*7+hh] - m[hh]);
      sm[hh] += e;
      atts[s*7+hh] = e;
    }
    aid[s] = a;
  }
  #pragma unroll
  for (int hh = 0; hh < 7; ++hh){
    float v = sm[hh];
    #pragma unroll
    for (int msk = 32; msk >= 1; msk >>= 1) v += __shfl_xor(v, msk);
    sm[hh] = 1.f / v;
  }
  for (int s = off + lane; s < end; s += 64){
    #pragma unroll
    for (int hh = 0; hh < 7; ++hh) atts[s*7+hh] *= sm[hh];
  }
}

// ================= BIG PATH: GEMM -> xmix (no atomics) ======================
// LDS: As bf16[128][40] @0 | Bs bf16[224][40] @10240 | eL u16[128][32] @28160
//      aL f32[128][7] @36352 ; phase2 xt bf16[128][232] @0 (59392)
#define G3_BS   10240
#define G3_EL   28160
#define G3_AL   36352
#define G3_TOT  59392

__global__ __launch_bounds__(256) void k_gemm3(const u16* __restrict__ edge,
    const float* __restrict__ atts, const u16* __restrict__ BT, u16* __restrict__ xmix){
  __shared__ __attribute__((aligned(16))) char smem[G3_TOT];
  u16*   As = (u16*)smem;
  u16*   Bs = (u16*)(smem + G3_BS);
  u16*   eL = (u16*)(smem + G3_EL);
  float* aL = (float*)(smem + G3_AL);
  int tid = threadIdx.x;
  int wave = tid >> 6, lane = tid & 63, l15 = lane & 15, quad = lane >> 4;
  int row0 = blockIdx.x * 128;

  for (int e = tid; e < 896; e += 256) aL[e] = atts[(size_t)row0*7 + e];
  for (int e = tid; e < 512; e += 256){
    int r = e >> 2, q = e & 3;
    *(uint4*)(eL + r*32 + q*8) = *(const uint4*)(edge + (size_t)(row0 + r)*32 + q*8);
  }
  floatx4 acc[2][14];
  #pragma unroll
  for (int mt = 0; mt < 2; ++mt)
    #pragma unroll
    for (int nt = 0; nt < 14; ++nt)
      acc[mt][nt] = (floatx4){0.f, 0.f, 0.f, 0.f};
  __syncthreads();

  for (int kt = 0; kt < 7; ++kt){
    int kk = kt * 32;
    for (int e = tid; e < 896; e += 256){
      int r = e >> 2, q = e & 3;
      *(uint4*)(Bs + r*40 + q*8) = *(const uint4*)(BT + (size_t)r*224 + kk + q*8);
    }
    for (int e = tid; e < 2048; e += 256){
      int r = e >> 4, c2 = (e & 15) * 2;
      int kc = kk + c2;
      int f0 = kc / 7,  h0 = kc - f0 * 7;
      int kc1 = kc + 1;
      int f1 = kc1 / 7, h1 = kc1 - f1 * 7;
      float v0 = b2f(eL[r*32 + f0]) * aL[r*7 + h0];
      float v1 = b2f(eL[r*32 + f1]) * aL[r*7 + h1];
      ((u32*)As)[r*20 + (e & 15)] = (u32)f2b(v0) | ((u32)f2b(v1) << 16);
    }
    __syncthreads();
    short8 a0 = *(const short8*)(As + (wave*32 + l15)*40 + quad*8);
    short8 a1 = *(const short8*)(As + (wave*32 + 16 + l15)*40 + quad*8);
    #pragma unroll
    for (int nt = 0; nt < 14; ++nt){
      short8 b = *(const short8*)(Bs + (nt*16 + l15)*40 + quad*8);
      acc[0][nt] = __builtin_amdgcn_mfma_f32_16x16x32_bf16(a0, b, acc[0][nt], 0, 0, 0);
      acc[1][nt] = __builtin_amdgcn_mfma_f32_16x16x32_bf16(a1, b, acc[1][nt], 0, 0, 0);
    }
    __syncthreads();
  }
  u16* xt = (u16*)smem;
  #pragma unroll
  for (int mt = 0; mt < 2; ++mt)
    #pragma unroll
    for (int nt = 0; nt < 14; ++nt)
      #pragma unroll
      for (int reg = 0; reg < 4; ++reg){
        int r = wave*32 + mt*16 + quad*4 + reg;
        int c = nt*16 + l15;
        float vv = acc[mt][nt][reg];
        vv = fminf(fmaxf(vv, -15.f), 15.f);
        float e2 = __expf(2.f * vv);
        xt[r*232 + c] = f2b((e2 - 1.f) / (e2 + 1.f));
      }
  __syncthreads();
  // coalesced copy out: 128 rows x 28 uint4
  for (int e = tid; e < 3584; e += 256){
    int r = e / 28, w = e - r * 28;
    *(uint4*)(xmix + (size_t)(row0 + r)*224 + w*8) = *(const uint4*)(xt + r*232 + w*8);
  }
}

// ---------------- final (big): local comb reduce from xmix ----------------
__global__ __launch_bounds__(256) void k_final3(const float* __restrict__ h, const float* __restrict__ x,
    const float* __restrict__ v, const float* __restrict__ Wf, const int* __restrict__ offs,
    const u16* __restrict__ edge, const float* __restrict__ atts, const float* __restrict__ dirs,
    const u16* __restrict__ xmix, float* __restrict__ out){
  __shared__ float s_hsem[224];
  __shared__ float s_nsq[224];
  __shared__ float s_pv[256][3];
  __shared__ float s_u1[32], s_sp[32], s_un[32], s_g[32];
  __shared__ float s_sc;
  int a = blockIdx.x;
  int tid = threadIdx.x;
  int off = offs[a], end = offs[a+1];
  int cnt = end - off;
  float inv = 1.f / fmaxf((float)cnt, 1.f);
  if (tid < 224){
    int f = tid / 7, hh = tid - f * 7;
    float c0 = 0.f, c1 = 0.f, c2 = 0.f, hsum = 0.f;
    for (int s = off; s < end; ++s){
      float xm = b2f(xmix[(size_t)s*224 + tid]);
      float d0 = dirs[s*3+0], d1 = dirs[s*3+1], d2 = dirs[s*3+2];
      c0 += d0 * xm; c1 += d1 * xm; c2 += d2 * xm;
      hsum += b2f(edge[(size_t)s*32 + f]) * atts[s*7 + hh];
    }
    s_hsem[tid] = hsum;
    float cm0 = c0 * inv, cm1 = c1 * inv, cm2 = c2 * inv;
    s_nsq[tid] = cm0*cm0 + cm1*cm1 + cm2*cm2;
    float wv = Wf[OFF_WVMIX + tid];
    s_pv[tid][0] = wv * cm0; s_pv[tid][1] = wv * cm1; s_pv[tid][2] = wv * cm2;
  } else {
    s_pv[tid][0] = 0.f; s_pv[tid][1] = 0.f; s_pv[tid][2] = 0.f;
  }
  __syncthreads();
  #pragma unroll
  for (int st = 128; st >= 1; st >>= 1){
    if (tid < st){
      s_pv[tid][0] += s_pv[tid + st][0];
      s_pv[tid][1] += s_pv[tid + st][1];
      s_pv[tid][2] += s_pv[tid + st][2];
    }
    __syncthreads();
  }
  if (tid < 32){
    float u = Wf[OFF_BP1 + tid];
    for (int c = 0; c < 224; ++c) u += s_nsq[c] * Wf[OFF_WP1 + c * 32 + tid];
    s_u1[tid] = siluf(u);
  }
  __syncthreads();
  if (tid < 32){
    float u = Wf[OFF_BP2 + tid];
    #pragma unroll
    for (int k = 0; k < 32; ++k) u += s_u1[k] * Wf[OFF_WP2 + k * 32 + tid];
    s_sp[tid] = siluf(u);
  }
  __syncthreads();
  if (tid < 32){
    float u = Wf[OFF_BN1 + tid];
    #pragma unroll
    for (int k = 0; k < 32; ++k) u += h[a*32+k] * Wf[OFF_WN1 + k * 32 + tid];
    for (int c = 0; c < 224; ++c) u += s_hsem[c] * Wf[OFF_WN1 + (32 + c) * 32 + tid];
    #pragma unroll
    for (int k = 0; k < 32; ++k) u += s_sp[k] * Wf[OFF_WN1 + (256 + k) * 32 + tid];
    s_un[tid] = siluf(u);
  }
  __syncthreads();
  if (tid < 32){
    float u = Wf[OFF_BN2 + tid];
    #pragma unroll
    for (int k = 0; k < 32; ++k) u += s_un[k] * Wf[OFF_WN2 + k * 32 + tid];
    out[a*32+tid] = h[a*32+tid] + siluf(u);
    float g = Wf[OFF_BV1 + tid];
    #pragma unroll
    for (int k = 0; k < 32; ++k) g += h[a*32+k] * Wf[OFF_WV1 + k * 32 + tid];
    s_g[tid] = siluf(g);
  }
  __syncthreads();
  if (tid == 0){
    float z = 0.f;
    #pragma unroll
    for (int k = 0; k < 32; ++k) z += s_g[k] * Wf[OFF_WV2 + k];
    s_sc = 2.f / (1.f + __expf(-z));
  }
  __syncthreads();
  if (tid < 3){
    float dv = s_pv[0][tid];
    float vup = s_sc * v[a*3+tid] + dv;
    float xup = x[a*3+tid] + vup;
    out[N_ATOMS*32 + a*3 + tid] = xup;
    out[N_ATOMS*32 + N_ATOMS*3 + a*3 + tid] = vup;
  }
}

// ================= SMALL PATH (fallback): round-8 atomic epilogue ===========
#define GLDS_BS   10240
#define GLDS_EL   28160
#define GLDS_AL   36352
#define GLDS_DL   59392
#define GLDS_ID   60928
#define GLDS_TOT  61440

__global__ __launch_bounds__(256) void k_gemm2b(const int* __restrict__ aid,
    const u16* __restrict__ edge, const float* __restrict__ atts,
    const float* __restrict__ dirs, const u16* __restrict__ BT, float* __restrict__ comb){
  __shared__ __attribute__((aligned(16))) char smem[GLDS_TOT];
  u16*   As = (u16*)smem;
  u16*   Bs = (u16*)(smem + GLDS_BS);
  u16*   eL = (u16*)(smem + GLDS_EL);
  float* aL = (float*)(smem + GLDS_AL);
  float* dL = (float*)(smem + GLDS_DL);
  int*  idL = (int*)(smem + GLDS_ID);
  int tid = threadIdx.x;
  int wave = tid >> 6, lane = tid & 63, l15 = lane & 15, quad = lane >> 4;
  int row0 = blockIdx.x * 128;

  if (tid < 128){
    idL[tid] = aid[row0 + tid];
    dL[tid*3+0] = dirs[(row0+tid)*3+0];
    dL[tid*3+1] = dirs[(row0+tid)*3+1];
    dL[tid*3+2] = dirs[(row0+tid)*3+2];
  }
  for (int e = tid; e < 896; e += 256) aL[e] = atts[(size_t)row0*7 + e];
  for (int e = tid; e < 512; e += 256){
    int r = e >> 2, q = e & 3;
    *(uint4*)(eL + r*32 + q*8) = *(const uint4*)(edge + (size_t)(row0 + r)*32 + q*8);
  }
  floatx4 acc[2][14];
  #pragma unroll
  for (int mt = 0; mt < 2; ++mt)
    #pragma unroll
    for (int nt = 0; nt < 14; ++nt)
      acc[mt][nt] = (floatx4){0.f, 0.f, 0.f, 0.f};
  __syncthreads();

  for (int kt = 0; kt < 7; ++kt){
    int kk = kt * 32;
    for (int e = tid; e < 896; e += 256){
      int r = e >> 2, q = e & 3;
      *(uint4*)(Bs + r*40 + q*8) = *(const uint4*)(BT + (size_t)r*224 + kk + q*8);
    }
    for (int e = tid; e < 2048; e += 256){
      int r = e >> 4, c2 = (e & 15) * 2;
      int kc = kk + c2;
      int f0 = kc / 7,  h0 = kc - f0 * 7;
      int kc1 = kc + 1;
      int f1 = kc1 / 7, h1 = kc1 - f1 * 7;
      float v0 = b2f(eL[r*32 + f0]) * aL[r*7 + h0];
      float v1 = b2f(eL[r*32 + f1]) * aL[r*7 + h1];
      ((u32*)As)[r*20 + (e & 15)] = (u32)f2b(v0) | ((u32)f2b(v1) << 16);
    }
    __syncthreads();
    short8 a0 = *(const short8*)(As + (wave*32 + l15)*40 + quad*8);
    short8 a1 = *(const short8*)(As + (wave*32 + 16 + l15)*40 + quad*8);
    #pragma unroll
    for (int nt = 0; nt < 14; ++nt){
      short8 b = *(const short8*)(Bs + (nt*16 + l15)*40 + quad*8);
      acc[0][nt] = __builtin_amdgcn_mfma_f32_16x16x32_bf16(a0, b, acc[0][nt], 0, 0, 0);
      acc[1][nt] = __builtin_amdgcn_mfma_f32_16x16x32_bf16(a1, b, acc[1][nt], 0, 0, 0);
    }
    __syncthreads();
  }
  u16* xt = (u16*)smem;
  #pragma unroll
  for (int mt = 0; mt < 2; ++mt)
    #pragma unroll
    for (int nt = 0; nt < 14; ++nt)
      #pragma unroll
      for (int reg = 0; reg < 4; ++reg){
        int r = wave*32 + mt*16 + quad*4 + reg;
        int c = nt*16 + l15;
        float vv = acc[mt][nt][reg];
        vv = fminf(fmaxf(vv, -15.f), 15.f);
        float e2 = __expf(2.f * vv);
        xt[r*232 + c] = f2b((e2 - 1.f) / (e2 + 1.f));
      }
  __syncthreads();
  if (tid < 224){
    int c = tid;
    int acur = idL[0];
    float s0 = 0.f, s1 = 0.f, s2 = 0.f;
    for (int r = 0; r < 128; ++r){
      int ar = idL[r];
      if (ar != acur){
        atomicAdd(&comb[((size_t)acur*224 + c)*3 + 0], s0);
        atomicAdd(&comb[((size_t)acur*224 + c)*3 + 1], s1);
        atomicAdd(&comb[((size_t)acur*224 + c)*3 + 2], s2);
        s0 = s1 = s2 = 0.f; acur = ar;
      }
      float xv = b2f(xt[r*232 + c]);
      s0 += dL[r*3+0] * xv;
      s1 += dL[r*3+1] * xv;
      s2 += dL[r*3+2] * xv;
    }
    atomicAdd(&comb[((size_t)acur*224 + c)*3 + 0], s0);
    atomicAdd(&comb[((size_t)acur*224 + c)*3 + 1], s1);
    atomicAdd(&comb[((size_t)acur*224 + c)*3 + 2], s2);
  }
}

__global__ __launch_bounds__(256) void k_finalb(const float* __restrict__ h, const float* __restrict__ x,
    const float* __restrict__ v, const float* __restrict__ Wf, const int* __restrict__ offs,
    const u16* __restrict__ edge, const float* __restrict__ atts,
    const float* __restrict__ comb, float* __restrict__ out){
  __shared__ float s_hsem[224];
  __shared__ float s_nsq[224];
  __shared__ float s_pv[256][3];
  __shared__ float s_u1[32], s_sp[32], s_un[32], s_g[32];
  __shared__ float s_sc;
  int a = blockIdx.x;
  int tid = threadIdx.x;
  int off = offs[a], end = offs[a+1];
  int cnt = end - off;
  float inv = 1.f / fmaxf((float)cnt, 1.f);
  if (tid < 224){
    int f = tid / 7, hh = tid - f * 7;
    float hsum = 0.f;
    for (int s = off; s < end; ++s)
      hsum += b2f(edge[(size_t)s*32 + f]) * atts[s*7 + hh];
    s_hsem[tid] = hsum;
    float cm0 = comb[((size_t)a*224 + tid)*3 + 0] * inv;
    float cm1 = comb[((size_t)a*224 + tid)*3 + 1] * inv;
    float cm2 = comb[((size_t)a*224 + tid)*3 + 2] * inv;
    s_nsq[tid] = cm0*cm0 + cm1*cm1 + cm2*cm2;
    float wv = Wf[OFF_WVMIX + tid];
    s_pv[tid][0] = wv * cm0; s_pv[tid][1] = wv * cm1; s_pv[tid][2] = wv * cm2;
  } else {
    s_pv[tid][0] = 0.f; s_pv[tid][1] = 0.f; s_pv[tid][2] = 0.f;
  }
  __syncthreads();
  #pragma unroll
  for (int st = 128; st >= 1; st >>= 1){
    if (tid < st){
      s_pv[tid][0] += s_pv[tid + st][0];
      s_pv[tid][1] += s_pv[tid + st][1];
      s_pv[tid][2] += s_pv[tid + st][2];
    }
    __syncthreads();
  }
  if (tid < 32){
    float u = Wf[OFF_BP1 + tid];
    for (int c = 0; c < 224; ++c) u += s_nsq[c] * Wf[OFF_WP1 + c * 32 + tid];
    s_u1[tid] = siluf(u);
  }
  __syncthreads();
  if (tid < 32){
    float u = Wf[OFF_BP2 + tid];
    #pragma unroll
    for (int k = 0; k < 32; ++k) u += s_u1[k] * Wf[OFF_WP2 + k * 32 + tid];
    s_sp[tid] = siluf(u);
  }
  __syncthreads();
  if (tid < 32){
    float u = Wf[OFF_BN1 + tid];
    #pragma unroll
    for (int k = 0; k < 32; ++k) u += h[a*32+k] * Wf[OFF_WN1 + k * 32 + tid];
    for (int c = 0; c < 224; ++c) u += s_hsem[c] * Wf[OFF_WN1 + (32 + c) * 32 + tid];
    #pragma unroll
    for (int k = 0; k < 32; ++k) u += s_sp[k] * Wf[OFF_WN1 + (256 + k) * 32 + tid];
    s_un[tid] = siluf(u);
  }
  __syncthreads();
  if (tid < 32){
    float u = Wf[OFF_BN2 + tid];
    #pragma unroll
    for (int k = 0; k < 32; ++k) u += s_un[k] * Wf[OFF_WN2 + k * 32 + tid];
    out[a*32+tid] = h[a*32+tid] + siluf(u);
    float g = Wf[OFF_BV1 + tid];
    #pragma unroll
    for (int k = 0; k < 32; ++k) g += h[a*32+k] * Wf[OFF_WV1 + k * 32 + tid];
    s_g[tid] = siluf(g);
  }
  __syncthreads();
  if (tid == 0){
    float z = 0.f;
    #pragma unroll
    for (int k = 0; k < 32; ++k) z += s_g[k] * Wf[OFF_WV2 + k];
    s_sc = 2.f / (1.f + __expf(-z));
  }
  __syncthreads();
  if (tid < 3){
    float dv = s_pv[0][tid];
    float vup = s_sc * v[a*3+tid] + dv;
    float xup = x[a*3+tid] + vup;
    out[N_ATOMS*32 + a*3 + tid] = xup;
    out[N_ATOMS*32 + N_ATOMS*3 + a*3 + tid] = vup;
  }
}

// ---------------- workspace layout ----------------
static constexpr size_t al256(size_t x){ return (x + 255) & ~(size_t)255; }
static constexpr size_t WS_FLAGS   = 0;
static constexpr size_t WS_COUNTS  = al256(WS_FLAGS + 8);
static constexpr size_t WS_OFFSETS = al256(WS_COUNTS + (size_t)N_ATOMS * 4);
static constexpr size_t WS_CURSOR  = al256(WS_OFFSETS + (size_t)(N_ATOMS + 1) * 4);
static constexpr size_t WS_PERM    = al256(WS_CURSOR + (size_t)N_ATOMS * 4);
static constexpr size_t WS_AID     = al256(WS_PERM + (size_t)P_PAIRS * 4);
static constexpr size_t WS_PLI     = al256(WS_AID + (size_t)P_PAIRS * 4);
static constexpr size_t WS_HF      = al256(WS_PLI + (size_t)2 * P_PAIRS * 4);
static constexpr size_t WS_XF      = al256(WS_HF + (size_t)N_ATOMS * 32 * 4);
static constexpr size_t WS_VF      = al256(WS_XF + (size_t)N_ATOMS * 3 * 4);
static constexpr size_t WS_WF      = al256(WS_VF + (size_t)N_ATOMS * 3 * 4);
static constexpr size_t WS_WT      = al256(WS_WF + (size_t)WF_TOTAL * 4);
static constexpr size_t WS_EDGE    = al256(WS_WT + (size_t)224 * 224 * 2);
static constexpr size_t WS_ATTS    = al256(WS_EDGE + (size_t)P_PAIRS * 32 * 2);
static constexpr size_t WS_DIRS    = al256(WS_ATTS + (size_t)P_PAIRS * 7 * 4);
static constexpr size_t WS_LOGITS  = al256(WS_DIRS + (size_t)P_PAIRS * 3 * 4);
// xmix (big) and comb (small) both alias the logits region (logits dead after k_att)
static constexpr size_t WS_END_BIG   = WS_LOGITS + (size_t)P_PAIRS * 224 * 2;
static constexpr size_t WS_END_SMALL = WS_LOGITS + (size_t)N_ATOMS * 224 * 3 * 4;

extern "C" void kernel_launch(void* const* d_in, const int* in_sizes, int n_in,
                              void* d_out, int out_size, void* d_ws, size_t ws_size,
                              hipStream_t stream){
  (void)in_sizes; (void)n_in;
  bool big = (ws_size >= WS_END_BIG);
  if (out_size != 380000 || (!big && ws_size < WS_END_SMALL)){
    k_code<<<1, 64, 0, stream>>>((float*)d_out, 14000.f);
    return;
  }
  char* ws = (char*)d_ws;
  int*   flags  = (int*)(ws + WS_FLAGS);
  int*   counts = (int*)(ws + WS_COUNTS);
  int*   offs   = (int*)(ws + WS_OFFSETS);
  int*   cursor = (int*)(ws + WS_CURSOR);
  int*   perm   = (int*)(ws + WS_PERM);
  int*   aid    = (int*)(ws + WS_AID);
  int*   pli    = (int*)(ws + WS_PLI);
  float* hf     = (float*)(ws + WS_HF);
  float* xf     = (float*)(ws + WS_XF);
  float* vf     = (float*)(ws + WS_VF);
  float* Wf     = (float*)(ws + WS_WF);
  u16*   wT     = (u16*)(ws + WS_WT);
  u16*   edge   = (u16*)(ws + WS_EDGE);
  float* atts   = (float*)(ws + WS_ATTS);
  float* dirs   = (float*)(ws + WS_DIRS);
  float* logits = (float*)(ws + WS_LOGITS);
  u16*   xmix   = (u16*)(ws + WS_LOGITS);     // alias (big path)
  float* comb   = (float*)(ws + WS_LOGITS);   // alias (small path)

  hipMemsetAsync(counts, 0, (size_t)N_ATOMS * 4, stream);
  k_detect<<<1, 64, 0, stream>>>((const u32*)d_in[0], (const u32*)d_in[3], flags);
  k_norm<<<(700000 + 255) / 256, 256, 0, stream>>>(d_in[0], d_in[1], d_in[2], d_in[3],
                                                   flags, hf, xf, vf, pli);
  k_convert<<<(WF_TOTAL + 255) / 256, 256, 0, stream>>>(
      d_in[4],  d_in[5],  d_in[6],  d_in[7],  d_in[8],  d_in[9],  d_in[10], d_in[11],
      d_in[12], d_in[13], d_in[14], d_in[15], d_in[16], d_in[17], d_in[18], d_in[19],
      d_in[20], d_in[21], d_in[22], d_in[24], flags, Wf);
  k_transpose<<<(224 * 224 + 255) / 256, 256, 0, stream>>>(d_in[23], flags, wT);
  k_hist<<<P_PAIRS / 256, 256, 0, stream>>>(pli, counts);
  k_scan<<<1, 256, 0, stream>>>(counts, offs, cursor);
  k_scatter<<<P_PAIRS / 256, 256, 0, stream>>>(pli, cursor, perm);
  k_pair<<<P_PAIRS / 256, 256, 0, stream>>>(hf, xf, pli, perm, Wf, edge, logits, dirs);
  k_att<<<N_ATOMS / 4, 256, 0, stream>>>(offs, logits, atts, aid);
  if (big){
    k_gemm3<<<P_PAIRS / 128, 256, 0, stream>>>(edge, atts, wT, xmix);
    k_final3<<<N_ATOMS, 256, 0, stream>>>(hf, xf, vf, Wf, offs, edge, atts, dirs, xmix, (float*)d_out);
  } else {
    hipMemsetAsync(comb, 0, (size_t)N_ATOMS * 224 * 3 * 4, stream);
    k_gemm2b<<<P_PAIRS / 128, 256, 0, stream>>>(aid, edge, atts, dirs, wT, comb);
    k_finalb<<<N_ATOMS, 256, 0, stream>>>(hf, xf, vf, Wf, offs, edge, atts, comb, (float*)d_out);
  }
}

// Round 10
// 461.700 us; speedup vs baseline: 3.8430x; 1.0053x over previous
//
#include <hip/hip_runtime.h>

typedef unsigned short u16;
typedef unsigned int u32;
typedef __attribute__((ext_vector_type(8))) short short8;
typedef __attribute__((ext_vector_type(4))) float floatx4;

#define P_PAIRS 160000
#define N_ATOMS 10000

#define OFF_WMLP  0
#define OFF_BMLP  3200
#define OFF_WE1   3250
#define OFF_BE1   6930
#define OFF_WE2   6962
#define OFF_BE2   7986
#define OFF_WATT  8018
#define OFF_BATT  8242
#define OFF_WN1   8249
#define OFF_BN1   17465
#define OFF_WN2   17497
#define OFF_BN2   18521
#define OFF_WP1   18553
#define OFF_BP1   25721
#define OFF_WP2   25753
#define OFF_BP2   26777
#define OFF_WV1   26809
#define OFF_BV1   27833
#define OFF_WV2   27865
#define OFF_WVMIX 27897
#define WF_TOTAL  28121

__device__ __forceinline__ float b2f(u16 u){ return __uint_as_float(((u32)u) << 16); }
__device__ __forceinline__ u16 f2b(float f){
  u32 u = __float_as_uint(f);
  u32 r = (u + 0x7FFFu + ((u >> 16) & 1u)) >> 16;
  return (u16)r;
}
__device__ __forceinline__ float siluf(float v){ return v / (1.f + __expf(-v)); }
__device__ __forceinline__ float ldw(const void* p, int o, int bf){
  return bf ? b2f(((const u16*)p)[o]) : ((const float*)p)[o];
}

__global__ void k_code(float* out, float code){
  if (threadIdx.x == 0 && blockIdx.x == 0) out[0] = code;
}

// ---------------- dtype detection ----------------
__global__ void k_detect(const u32* __restrict__ hw, const u32* __restrict__ plw,
                         int* __restrict__ flags){
  if (threadIdx.x == 0 && blockIdx.x == 0){
    int bf = 0;
    for (int k = 0; k < 64; ++k){
      u32 e = (hw[k] >> 7) & 0xFFu;
      if (e >= 100u && e <= 140u) bf++;
    }
    flags[0] = (bf >= 48) ? 1 : 0;
    int z = 0;
    for (int k = 0; k < 64; ++k) if (plw[2*k+1] == 0u) z++;
    flags[1] = (z >= 60) ? 1 : 0;
  }
}

// ---------------- input normalization ----------------
__global__ void k_norm(const void* __restrict__ h_raw, const void* __restrict__ x_raw,
                       const void* __restrict__ v_raw, const void* __restrict__ pl_raw,
                       const int* __restrict__ flags, float* __restrict__ hf,
                       float* __restrict__ xf, float* __restrict__ vf, int* __restrict__ pli){
  int t = blockIdx.x * 256 + threadIdx.x;
  int bf = flags[0], i64 = flags[1];
  if (t < 320000){
    hf[t] = ldw(h_raw, t, bf);
  } else if (t < 350000){
    int i = t - 320000;
    xf[i] = ldw(x_raw, i, bf);
  } else if (t < 380000){
    int i = t - 350000;
    vf[i] = ldw(v_raw, i, bf);
  } else if (t < 700000){
    int k = t - 380000;
    const int* p32 = (const int*)pl_raw;
    pli[k] = i64 ? p32[2*(size_t)k] : p32[k];
  }
}

// ---------------- weight conversion -> fp32 ----------------
__global__ void k_convert(const void* w_mlp, const void* b_mlp, const void* w_e1, const void* b_e1,
  const void* w_e2, const void* b_e2, const void* w_att, const void* b_att,
  const void* w_n1, const void* b_n1, const void* w_n2, const void* b_n2,
  const void* w_p1, const void* b_p1, const void* w_p2, const void* b_p2,
  const void* w_v1, const void* b_v1, const void* w_v2, const void* w_vmix,
  const int* __restrict__ flags, float* __restrict__ Wf){
  int t = blockIdx.x * 256 + threadIdx.x;
  if (t >= WF_TOTAL) return;
  int bf = flags[0];
  const void* src; int o;
  if      (t < 3200)  { src = w_mlp;  o = t; }
  else if (t < 3250)  { src = b_mlp;  o = t - 3200; }
  else if (t < 6930)  { src = w_e1;   o = t - 3250; }
  else if (t < 6962)  { src = b_e1;   o = t - 6930; }
  else if (t < 7986)  { src = w_e2;   o = t - 6962; }
  else if (t < 8018)  { src = b_e2;   o = t - 7986; }
  else if (t < 8242)  { src = w_att;  o = t - 8018; }
  else if (t < 8249)  { src = b_att;  o = t - 8242; }
  else if (t < 17465) { src = w_n1;   o = t - 8249; }
  else if (t < 17497) { src = b_n1;   o = t - 17465; }
  else if (t < 18521) { src = w_n2;   o = t - 17497; }
  else if (t < 18553) { src = b_n2;   o = t - 18521; }
  else if (t < 25721) { src = w_p1;   o = t - 18553; }
  else if (t < 25753) { src = b_p1;   o = t - 25721; }
  else if (t < 26777) { src = w_p2;   o = t - 25753; }
  else if (t < 26809) { src = b_p2;   o = t - 26777; }
  else if (t < 27833) { src = w_v1;   o = t - 26809; }
  else if (t < 27865) { src = b_v1;   o = t - 27833; }
  else if (t < 27897) { src = w_v2;   o = t - 27865; }
  else                { src = w_vmix; o = t - 27897; }
  Wf[t] = ldw(src, o, bf);
}

// wT[n][k] = w_xmix[k][n] as bf16 (B^T operand for MFMA)
__global__ void k_transpose(const void* __restrict__ wx, const int* __restrict__ flags,
                            u16* __restrict__ wT){
  int t = blockIdx.x * 256 + threadIdx.x;
  if (t >= 224 * 224) return;
  int n = t / 224, k = t - n * 224;
  wT[t] = f2b(ldw(wx, k * 224 + n, flags[0]));
}

// ---------------- counting sort ----------------
__global__ void k_hist(const int* __restrict__ pl, int* __restrict__ counts){
  int p = blockIdx.x * 256 + threadIdx.x;
  atomicAdd(&counts[pl[p]], 1);
}

__global__ void k_scan(const int* __restrict__ counts, int* __restrict__ offs, int* __restrict__ cursor){
  __shared__ int part[256];
  int t = threadIdx.x;
  int sum = 0;
  for (int k = 0; k < 40; ++k){
    int idx = t * 40 + k;
    if (idx < N_ATOMS) sum += counts[idx];
  }
  part[t] = sum;
  __syncthreads();
  if (t == 0){
    int run = 0;
    for (int q = 0; q < 256; ++q){ int tmp = part[q]; part[q] = run; run += tmp; }
  }
  __syncthreads();
  int run = part[t];
  for (int k = 0; k < 40; ++k){
    int idx = t * 40 + k;
    if (idx < N_ATOMS){ offs[idx] = run; cursor[idx] = run; run += counts[idx]; }
  }
  if (t == 0) offs[N_ATOMS] = P_PAIRS;
}

__global__ void k_scatter(const int* __restrict__ pl, int* __restrict__ cursor, int* __restrict__ perm){
  int p = blockIdx.x * 256 + threadIdx.x;
  int i = pl[p];
  int pos = atomicAdd(&cursor[i], 1);
  perm[pos] = p;
}

// ---------------- per-pair edge model (sorted slots, reg-cached h) ---------
__global__ __launch_bounds__(256) void k_pair(const float* __restrict__ h, const float* __restrict__ x,
    const int* __restrict__ pl, const int* __restrict__ perm, const float* __restrict__ Wf,
    u16* __restrict__ edge, float* __restrict__ logits, float* __restrict__ dirs){
  int tid = threadIdx.x;
  int s = blockIdx.x * 256 + tid;            // sorted slot
  int p = perm[s];
  int i = pl[p], j = pl[P_PAIRS + p];
  float hl[64];
  {
    const float4* a4 = (const float4*)(h + (size_t)i * 32);
    const float4* b4 = (const float4*)(h + (size_t)j * 32);
    #pragma unroll
    for (int q = 0; q < 8; ++q){
      float4 t = a4[q];
      hl[q*4+0] = t.x; hl[q*4+1] = t.y; hl[q*4+2] = t.z; hl[q*4+3] = t.w;
    }
    #pragma unroll
    for (int q = 0; q < 8; ++q){
      float4 t = b4[q];
      hl[32+q*4+0] = t.x; hl[32+q*4+1] = t.y; hl[32+q*4+2] = t.z; hl[32+q*4+3] = t.w;
    }
  }
  float r0 = x[j*3+0] - x[i*3+0];
  float r1 = x[j*3+1] - x[i*3+1];
  float r2 = x[j*3+2] - x[i*3+2];
  float d = sqrtf(r0*r0 + r1*r1 + r2*r2);
  float rinv = 1.f / (d + 1e-5f);
  dirs[s*3+0] = r0*rinv; dirs[s*3+1] = r1*rinv; dirs[s*3+2] = r2*rinv;

  float filt[50];
  #pragma unroll
  for (int o = 0; o < 50; ++o) filt[o] = Wf[OFF_BMLP + o];
  for (int k = 0; k < 64; ++k){
    float hk = hl[k];
    const float* wr = Wf + OFF_WMLP + k * 50;
    #pragma unroll
    for (int o = 0; o < 50; ++o) filt[o] += hk * wr[o];
  }
  #pragma unroll
  for (int o = 0; o < 50; ++o){
    float c = (float)o * (5.0f / 49.0f);
    float dd = d - c;
    filt[o] *= __expf(-10.0f * dd * dd);
  }
  float u[32];
  #pragma unroll
  for (int o = 0; o < 32; ++o) u[o] = Wf[OFF_BE1 + o];
  for (int k = 0; k < 64; ++k){
    float ek = hl[k];
    const float* wr = Wf + OFF_WE1 + k * 32;
    #pragma unroll
    for (int o = 0; o < 32; ++o) u[o] += ek * wr[o];
  }
  #pragma unroll
  for (int kk = 0; kk < 50; ++kk){
    const float* wr = Wf + OFF_WE1 + (64 + kk) * 32;
    #pragma unroll
    for (int o = 0; o < 32; ++o) u[o] += filt[kk] * wr[o];
  }
  {
    const float* wr = Wf + OFF_WE1 + 114 * 32;
    #pragma unroll
    for (int o = 0; o < 32; ++o) u[o] += d * wr[o];
  }
  #pragma unroll
  for (int o = 0; o < 32; ++o) u[o] = siluf(u[o]);
  float eg[32];
  #pragma unroll
  for (int o = 0; o < 32; ++o) eg[o] = Wf[OFF_BE2 + o];
  #pragma unroll
  for (int k = 0; k < 32; ++k){
    const float* wr = Wf + OFF_WE2 + k * 32;
    #pragma unroll
    for (int o = 0; o < 32; ++o) eg[o] += u[k] * wr[o];
  }
  {
    u32 st[16];
    #pragma unroll
    for (int o = 0; o < 16; ++o)
      st[o] = (u32)f2b(eg[2*o]) | ((u32)f2b(eg[2*o+1]) << 16);
    #pragma unroll
    for (int q = 0; q < 4; ++q){
      uint4 vv; vv.x = st[4*q]; vv.y = st[4*q+1]; vv.z = st[4*q+2]; vv.w = st[4*q+3];
      *(uint4*)(edge + (size_t)s * 32 + q * 8) = vv;
    }
  }
  float lg[7];
  #pragma unroll
  for (int o = 0; o < 7; ++o) lg[o] = Wf[OFF_BATT + o];
  #pragma unroll
  for (int k = 0; k < 32; ++k){
    const float* wr = Wf + OFF_WATT + k * 7;
    #pragma unroll
    for (int o = 0; o < 7; ++o) lg[o] += eg[k] * wr[o];
  }
  #pragma unroll
  for (int o = 0; o < 7; ++o){
    float vv = lg[o];
    float cl = vv > 0.f ? vv : 2.f * expm1f(0.5f * vv);
    logits[s*7+o] = cl;
  }
}

// ---------------- segment softmax: 16-lane group per atom ----------------
__global__ __launch_bounds__(256) void k_att(const int* __restrict__ offs,
    const float* __restrict__ logits, float* __restrict__ atts){
  int a = blockIdx.x * 16 + (threadIdx.x >> 4);   // N = 625*16
  int lane = threadIdx.x & 15;
  int off = offs[a], end = offs[a+1];
  float m[7];
  #pragma unroll
  for (int hh = 0; hh < 7; ++hh) m[hh] = -1e30f;
  for (int s = off + lane; s < end; s += 16){
    #pragma unroll
    for (int hh = 0; hh < 7; ++hh) m[hh] = fmaxf(m[hh], logits[s*7+hh]);
  }
  #pragma unroll
  for (int hh = 0; hh < 7; ++hh){
    float v = m[hh];
    #pragma unroll
    for (int msk = 8; msk >= 1; msk >>= 1) v = fmaxf(v, __shfl_xor(v, msk));
    m[hh] = v;
  }
  float sm[7] = {0,0,0,0,0,0,0};
  for (int s = off + lane; s < end; s += 16){
    #pragma unroll
    for (int hh = 0; hh < 7; ++hh){
      float e = __expf(logits[s*7+hh] - m[hh]);
      sm[hh] += e;
      atts[s*7+hh] = e;
    }
  }
  #pragma unroll
  for (int hh = 0; hh < 7; ++hh){
    float v = sm[hh];
    #pragma unroll
    for (int msk = 8; msk >= 1; msk >>= 1) v += __shfl_xor(v, msk);
    sm[hh] = 1.f / v;
  }
  for (int s = off + lane; s < end; s += 16){
    #pragma unroll
    for (int hh = 0; hh < 7; ++hh) atts[s*7+hh] *= sm[hh];
  }
}

// ---------------- MFMA GEMM -> xmix (no atomics) ----------------
#define G3_BS   10240
#define G3_EL   28160
#define G3_AL   36352
#define G3_TOT  59392

__global__ __launch_bounds__(256) void k_gemm3(const u16* __restrict__ edge,
    const float* __restrict__ atts, const u16* __restrict__ BT, u16* __restrict__ xmix){
  __shared__ __attribute__((aligned(16))) char smem[G3_TOT];
  u16*   As = (u16*)smem;
  u16*   Bs = (u16*)(smem + G3_BS);
  u16*   eL = (u16*)(smem + G3_EL);
  float* aL = (float*)(smem + G3_AL);
  int tid = threadIdx.x;
  int wave = tid >> 6, lane = tid & 63, l15 = lane & 15, quad = lane >> 4;
  int row0 = blockIdx.x * 128;

  for (int e = tid; e < 896; e += 256) aL[e] = atts[(size_t)row0*7 + e];
  for (int e = tid; e < 512; e += 256){
    int r = e >> 2, q = e & 3;
    *(uint4*)(eL + r*32 + q*8) = *(const uint4*)(edge + (size_t)(row0 + r)*32 + q*8);
  }
  floatx4 acc[2][14];
  #pragma unroll
  for (int mt = 0; mt < 2; ++mt)
    #pragma unroll
    for (int nt = 0; nt < 14; ++nt)
      acc[mt][nt] = (floatx4){0.f, 0.f, 0.f, 0.f};
  __syncthreads();

  for (int kt = 0; kt < 7; ++kt){
    int kk = kt * 32;
    for (int e = tid; e < 896; e += 256){
      int r = e >> 2, q = e & 3;
      *(uint4*)(Bs + r*40 + q*8) = *(const uint4*)(BT + (size_t)r*224 + kk + q*8);
    }
    for (int e = tid; e < 2048; e += 256){
      int r = e >> 4, c2 = (e & 15) * 2;
      int kc = kk + c2;
      int f0 = kc / 7,  h0 = kc - f0 * 7;
      int kc1 = kc + 1;
      int f1 = kc1 / 7, h1 = kc1 - f1 * 7;
      float v0 = b2f(eL[r*32 + f0]) * aL[r*7 + h0];
      float v1 = b2f(eL[r*32 + f1]) * aL[r*7 + h1];
      ((u32*)As)[r*20 + (e & 15)] = (u32)f2b(v0) | ((u32)f2b(v1) << 16);
    }
    __syncthreads();
    short8 a0 = *(const short8*)(As + (wave*32 + l15)*40 + quad*8);
    short8 a1 = *(const short8*)(As + (wave*32 + 16 + l15)*40 + quad*8);
    #pragma unroll
    for (int nt = 0; nt < 14; ++nt){
      short8 b = *(const short8*)(Bs + (nt*16 + l15)*40 + quad*8);
      acc[0][nt] = __builtin_amdgcn_mfma_f32_16x16x32_bf16(a0, b, acc[0][nt], 0, 0, 0);
      acc[1][nt] = __builtin_amdgcn_mfma_f32_16x16x32_bf16(a1, b, acc[1][nt], 0, 0, 0);
    }
    __syncthreads();
  }
  u16* xt = (u16*)smem;
  #pragma unroll
  for (int mt = 0; mt < 2; ++mt)
    #pragma unroll
    for (int nt = 0; nt < 14; ++nt)
      #pragma unroll
      for (int reg = 0; reg < 4; ++reg){
        int r = wave*32 + mt*16 + quad*4 + reg;
        int c = nt*16 + l15;
        float vv = acc[mt][nt][reg];
        vv = fminf(fmaxf(vv, -15.f), 15.f);
        float e2 = __expf(2.f * vv);
        xt[r*232 + c] = f2b((e2 - 1.f) / (e2 + 1.f));
      }
  __syncthreads();
  for (int e = tid; e < 3584; e += 256){
    int r = e / 28, w = e - r * 28;
    *(uint4*)(xmix + (size_t)(row0 + r)*224 + w*8) = *(const uint4*)(xt + r*232 + w*8);
  }
}

// ---------------- final: wave per atom ----------------
__global__ __launch_bounds__(256) void k_final4(const float* __restrict__ h, const float* __restrict__ x,
    const float* __restrict__ v, const float* __restrict__ Wf, const int* __restrict__ offs,
    const u16* __restrict__ edge, const float* __restrict__ atts, const float* __restrict__ dirs,
    const u16* __restrict__ xmix, float* __restrict__ out){
  __shared__ float s_nsq[4][224];
  __shared__ float s_hsem[4][224];
  __shared__ float s_u1[4][32], s_sp[4][32], s_g[4][32], s_un[4][32];
  int wv_ = threadIdx.x >> 6, lane = threadIdx.x & 63;
  int a = blockIdx.x * 4 + wv_;                 // N = 2500*4
  int off = offs[a], end = offs[a+1];
  int cnt = end - off;
  float inv = 1.f / fmaxf((float)cnt, 1.f);
  int cbase = lane * 4;
  float c0[4] = {0,0,0,0}, c1[4] = {0,0,0,0}, c2[4] = {0,0,0,0}, hs[4] = {0,0,0,0};
  int f_[4], hh_[4];
  #pragma unroll
  for (int j = 0; j < 4; ++j){
    int c = cbase + j;
    int cf = (c < 224) ? c : 0;
    f_[j] = cf / 7; hh_[j] = cf - f_[j] * 7;
  }
  if (lane < 56){
    for (int s = off; s < end; ++s){
      uint2 xm2 = *(const uint2*)(xmix + (size_t)s * 224 + cbase);
      float d0 = dirs[s*3+0], d1 = dirs[s*3+1], d2 = dirs[s*3+2];
      u16 xs[4] = {(u16)(xm2.x & 0xFFFFu), (u16)(xm2.x >> 16),
                   (u16)(xm2.y & 0xFFFFu), (u16)(xm2.y >> 16)};
      #pragma unroll
      for (int j = 0; j < 4; ++j){
        float xm = b2f(xs[j]);
        c0[j] += d0 * xm; c1[j] += d1 * xm; c2[j] += d2 * xm;
        hs[j] += b2f(edge[(size_t)s*32 + f_[j]]) * atts[s*7 + hh_[j]];
      }
    }
  }
  float pv0 = 0.f, pv1 = 0.f, pv2 = 0.f;
  if (lane < 56){
    #pragma unroll
    for (int j = 0; j < 4; ++j){
      int c = cbase + j;
      float cm0 = c0[j]*inv, cm1 = c1[j]*inv, cm2 = c2[j]*inv;
      s_nsq[wv_][c] = cm0*cm0 + cm1*cm1 + cm2*cm2;
      s_hsem[wv_][c] = hs[j];
      float wvx = Wf[OFF_WVMIX + c];
      pv0 += wvx*cm0; pv1 += wvx*cm1; pv2 += wvx*cm2;
    }
  }
  #pragma unroll
  for (int m = 32; m >= 1; m >>= 1){
    pv0 += __shfl_xor(pv0, m); pv1 += __shfl_xor(pv1, m); pv2 += __shfl_xor(pv2, m);
  }
  __syncthreads();
  if (lane < 32){
    float u = Wf[OFF_BP1 + lane];
    for (int c = 0; c < 224; ++c) u += s_nsq[wv_][c] * Wf[OFF_WP1 + c*32 + lane];
    s_u1[wv_][lane] = siluf(u);
    float g = Wf[OFF_BV1 + lane];
    #pragma unroll
    for (int k = 0; k < 32; ++k) g += h[a*32+k] * Wf[OFF_WV1 + k*32 + lane];
    s_g[wv_][lane] = siluf(g);
  }
  __syncthreads();
  float zpart = (lane < 32) ? s_g[wv_][lane] * Wf[OFF_WV2 + lane] : 0.f;
  #pragma unroll
  for (int m = 32; m >= 1; m >>= 1) zpart += __shfl_xor(zpart, m);
  float sc = 2.f / (1.f + __expf(-zpart));
  if (lane < 32){
    float u = Wf[OFF_BP2 + lane];
    #pragma unroll
    for (int k = 0; k < 32; ++k) u += s_u1[wv_][k] * Wf[OFF_WP2 + k*32 + lane];
    s_sp[wv_][lane] = siluf(u);
  }
  __syncthreads();
  if (lane < 32){
    float u = Wf[OFF_BN1 + lane];
    #pragma unroll
    for (int k = 0; k < 32; ++k) u += h[a*32+k] * Wf[OFF_WN1 + k*32 + lane];
    for (int c = 0; c < 224; ++c) u += s_hsem[wv_][c] * Wf[OFF_WN1 + (32 + c)*32 + lane];
    #pragma unroll
    for (int k = 0; k < 32; ++k) u += s_sp[wv_][k] * Wf[OFF_WN1 + (256 + k)*32 + lane];
    s_un[wv_][lane] = siluf(u);
  }
  __syncthreads();
  if (lane < 32){
    float u = Wf[OFF_BN2 + lane];
    #pragma unroll
    for (int k = 0; k < 32; ++k) u += s_un[wv_][k] * Wf[OFF_WN2 + k*32 + lane];
    out[a*32+lane] = h[a*32+lane] + siluf(u);
  }
  if (lane < 3){
    float vup = sc * v[a*3+lane] + ((lane == 0) ? pv0 : (lane == 1) ? pv1 : pv2);
    float xup = x[a*3+lane] + vup;
    out[N_ATOMS*32 + a*3 + lane] = xup;
    out[N_ATOMS*32 + N_ATOMS*3 + a*3 + lane] = vup;
  }
}

// ---------------- workspace layout (~93 MB, proven in round 9) ----------------
static constexpr size_t al256(size_t x){ return (x + 255) & ~(size_t)255; }
static constexpr size_t WS_FLAGS   = 0;
static constexpr size_t WS_COUNTS  = al256(WS_FLAGS + 8);
static constexpr size_t WS_OFFSETS = al256(WS_COUNTS + (size_t)N_ATOMS * 4);
static constexpr size_t WS_CURSOR  = al256(WS_OFFSETS + (size_t)(N_ATOMS + 1) * 4);
static constexpr size_t WS_PERM    = al256(WS_CURSOR + (size_t)N_ATOMS * 4);
static constexpr size_t WS_PLI     = al256(WS_PERM + (size_t)P_PAIRS * 4);
static constexpr size_t WS_HF      = al256(WS_PLI + (size_t)2 * P_PAIRS * 4);
static constexpr size_t WS_XF      = al256(WS_HF + (size_t)N_ATOMS * 32 * 4);
static constexpr size_t WS_VF      = al256(WS_XF + (size_t)N_ATOMS * 3 * 4);
static constexpr size_t WS_WF      = al256(WS_VF + (size_t)N_ATOMS * 3 * 4);
static constexpr size_t WS_WT      = al256(WS_WF + (size_t)WF_TOTAL * 4);
static constexpr size_t WS_EDGE    = al256(WS_WT + (size_t)224 * 224 * 2);
static constexpr size_t WS_ATTS    = al256(WS_EDGE + (size_t)P_PAIRS * 32 * 2);
static constexpr size_t WS_DIRS    = al256(WS_ATTS + (size_t)P_PAIRS * 7 * 4);
static constexpr size_t WS_LOGITS  = al256(WS_DIRS + (size_t)P_PAIRS * 3 * 4);
static constexpr size_t WS_END     = WS_LOGITS + (size_t)P_PAIRS * 224 * 2;   // xmix aliases logits

extern "C" void kernel_launch(void* const* d_in, const int* in_sizes, int n_in,
                              void* d_out, int out_size, void* d_ws, size_t ws_size,
                              hipStream_t stream){
  (void)in_sizes; (void)n_in;
  if (out_size != 380000 || ws_size < WS_END){
    k_code<<<1, 64, 0, stream>>>((float*)d_out, 14000.f);
    return;
  }
  char* ws = (char*)d_ws;
  int*   flags  = (int*)(ws + WS_FLAGS);
  int*   counts = (int*)(ws + WS_COUNTS);
  int*   offs   = (int*)(ws + WS_OFFSETS);
  int*   cursor = (int*)(ws + WS_CURSOR);
  int*   perm   = (int*)(ws + WS_PERM);
  int*   pli    = (int*)(ws + WS_PLI);
  float* hf     = (float*)(ws + WS_HF);
  float* xf     = (float*)(ws + WS_XF);
  float* vf     = (float*)(ws + WS_VF);
  float* Wf     = (float*)(ws + WS_WF);
  u16*   wT     = (u16*)(ws + WS_WT);
  u16*   edge   = (u16*)(ws + WS_EDGE);
  float* atts   = (float*)(ws + WS_ATTS);
  float* dirs   = (float*)(ws + WS_DIRS);
  float* logits = (float*)(ws + WS_LOGITS);
  u16*   xmix   = (u16*)(ws + WS_LOGITS);     // alias; logits dead after k_att

  hipMemsetAsync(counts, 0, (size_t)N_ATOMS * 4, stream);
  k_detect<<<1, 64, 0, stream>>>((const u32*)d_in[0], (const u32*)d_in[3], flags);
  k_norm<<<(700000 + 255) / 256, 256, 0, stream>>>(d_in[0], d_in[1], d_in[2], d_in[3],
                                                   flags, hf, xf, vf, pli);
  k_convert<<<(WF_TOTAL + 255) / 256, 256, 0, stream>>>(
      d_in[4],  d_in[5],  d_in[6],  d_in[7],  d_in[8],  d_in[9],  d_in[10], d_in[11],
      d_in[12], d_in[13], d_in[14], d_in[15], d_in[16], d_in[17], d_in[18], d_in[19],
      d_in[20], d_in[21], d_in[22], d_in[24], flags, Wf);
  k_transpose<<<(224 * 224 + 255) / 256, 256, 0, stream>>>(d_in[23], flags, wT);
  k_hist<<<P_PAIRS / 256, 256, 0, stream>>>(pli, counts);
  k_scan<<<1, 256, 0, stream>>>(counts, offs, cursor);
  k_scatter<<<P_PAIRS / 256, 256, 0, stream>>>(pli, cursor, perm);
  k_pair<<<P_PAIRS / 256, 256, 0, stream>>>(hf, xf, pli, perm, Wf, edge, logits, dirs);
  k_att<<<N_ATOMS / 16, 256, 0, stream>>>(offs, logits, atts);
  k_gemm3<<<P_PAIRS / 128, 256, 0, stream>>>(edge, atts, wT, xmix);
  k_final4<<<N_ATOMS / 4, 256, 0, stream>>>(hf, xf, vf, Wf, offs, edge, atts, dirs, xmix, (float*)d_out);
}

// Round 11
// 419.496 us; speedup vs baseline: 4.2296x; 1.1006x over previous
//
#include <hip/hip_runtime.h>

typedef unsigned short u16;
typedef unsigned int u32;
typedef __attribute__((ext_vector_type(8))) short short8;
typedef __attribute__((ext_vector_type(4))) float floatx4;

#define P_PAIRS 160000
#define N_ATOMS 10000

#define OFF_WMLP  0      // stored TRANSPOSED: [50][64], (o,k) at o*64+k
#define OFF_BMLP  3200
#define OFF_WE1   3250
#define OFF_BE1   6930
#define OFF_WE2   6962
#define OFF_BE2   7986
#define OFF_WATT  8018
#define OFF_BATT  8242
#define OFF_WN1   8249
#define OFF_BN1   17465
#define OFF_WN2   17497
#define OFF_BN2   18521
#define OFF_WP1   18553
#define OFF_BP1   25721
#define OFF_WP2   25753
#define OFF_BP2   26777
#define OFF_WV1   26809
#define OFF_BV1   27833
#define OFF_WV2   27865
#define OFF_WVMIX 27897
#define WF_TOTAL  28121

__device__ __forceinline__ float b2f(u16 u){ return __uint_as_float(((u32)u) << 16); }
__device__ __forceinline__ u16 f2b(float f){
  u32 u = __float_as_uint(f);
  u32 r = (u + 0x7FFFu + ((u >> 16) & 1u)) >> 16;
  return (u16)r;
}
__device__ __forceinline__ float siluf(float v){ return v / (1.f + __expf(-v)); }
__device__ __forceinline__ float ldw(const void* p, int o, int bf){
  return bf ? b2f(((const u16*)p)[o]) : ((const float*)p)[o];
}

__global__ void k_code(float* out, float code){
  if (threadIdx.x == 0 && blockIdx.x == 0) out[0] = code;
}

// ---------------- dtype detection ----------------
__global__ void k_detect(const u32* __restrict__ hw, const u32* __restrict__ plw,
                         int* __restrict__ flags){
  if (threadIdx.x == 0 && blockIdx.x == 0){
    int bf = 0;
    for (int k = 0; k < 64; ++k){
      u32 e = (hw[k] >> 7) & 0xFFu;
      if (e >= 100u && e <= 140u) bf++;
    }
    flags[0] = (bf >= 48) ? 1 : 0;
    int z = 0;
    for (int k = 0; k < 64; ++k) if (plw[2*k+1] == 0u) z++;
    flags[1] = (z >= 60) ? 1 : 0;
  }
}

// ---------------- input normalization ----------------
__global__ void k_norm(const void* __restrict__ h_raw, const void* __restrict__ x_raw,
                       const void* __restrict__ v_raw, const void* __restrict__ pl_raw,
                       const int* __restrict__ flags, float* __restrict__ hf,
                       float* __restrict__ xf, float* __restrict__ vf, int* __restrict__ pli){
  int t = blockIdx.x * 256 + threadIdx.x;
  int bf = flags[0], i64 = flags[1];
  if (t < 320000){
    hf[t] = ldw(h_raw, t, bf);
  } else if (t < 350000){
    int i = t - 320000;
    xf[i] = ldw(x_raw, i, bf);
  } else if (t < 380000){
    int i = t - 350000;
    vf[i] = ldw(v_raw, i, bf);
  } else if (t < 700000){
    int k = t - 380000;
    const int* p32 = (const int*)pl_raw;
    pli[k] = i64 ? p32[2*(size_t)k] : p32[k];
  }
}

// ---------------- weight conversion -> fp32 (WMLP stored transposed) --------
__global__ void k_convert(const void* w_mlp, const void* b_mlp, const void* w_e1, const void* b_e1,
  const void* w_e2, const void* b_e2, const void* w_att, const void* b_att,
  const void* w_n1, const void* b_n1, const void* w_n2, const void* b_n2,
  const void* w_p1, const void* b_p1, const void* w_p2, const void* b_p2,
  const void* w_v1, const void* b_v1, const void* w_v2, const void* w_vmix,
  const int* __restrict__ flags, float* __restrict__ Wf){
  int t = blockIdx.x * 256 + threadIdx.x;
  if (t >= WF_TOTAL) return;
  int bf = flags[0];
  if (t < 3200){
    int k = t / 50, o = t - k * 50;           // src (k,o) row-major [64][50]
    Wf[OFF_WMLP + o * 64 + k] = ldw(w_mlp, t, bf);
    return;
  }
  const void* src; int o;
  if      (t < 3250)  { src = b_mlp;  o = t - 3200; }
  else if (t < 6930)  { src = w_e1;   o = t - 3250; }
  else if (t < 6962)  { src = b_e1;   o = t - 6930; }
  else if (t < 7986)  { src = w_e2;   o = t - 6962; }
  else if (t < 8018)  { src = b_e2;   o = t - 7986; }
  else if (t < 8242)  { src = w_att;  o = t - 8018; }
  else if (t < 8249)  { src = b_att;  o = t - 8242; }
  else if (t < 17465) { src = w_n1;   o = t - 8249; }
  else if (t < 17497) { src = b_n1;   o = t - 17465; }
  else if (t < 18521) { src = w_n2;   o = t - 17497; }
  else if (t < 18553) { src = b_n2;   o = t - 18521; }
  else if (t < 25721) { src = w_p1;   o = t - 18553; }
  else if (t < 25753) { src = b_p1;   o = t - 25721; }
  else if (t < 26777) { src = w_p2;   o = t - 25753; }
  else if (t < 26809) { src = b_p2;   o = t - 26777; }
  else if (t < 27833) { src = w_v1;   o = t - 26809; }
  else if (t < 27865) { src = b_v1;   o = t - 27833; }
  else if (t < 27897) { src = w_v2;   o = t - 27865; }
  else                { src = w_vmix; o = t - 27897; }
  Wf[t] = ldw(src, o, bf);
}

// wT[n][k] = w_xmix[k][n] as bf16 (B^T operand for MFMA)
__global__ void k_transpose(const void* __restrict__ wx, const int* __restrict__ flags,
                            u16* __restrict__ wT){
  int t = blockIdx.x * 256 + threadIdx.x;
  if (t >= 224 * 224) return;
  int n = t / 224, k = t - n * 224;
  wT[t] = f2b(ldw(wx, k * 224 + n, flags[0]));
}

// ---------------- counting sort ----------------
__global__ void k_hist(const int* __restrict__ pl, int* __restrict__ counts){
  int p = blockIdx.x * 256 + threadIdx.x;
  atomicAdd(&counts[pl[p]], 1);
}

__global__ void k_scan(const int* __restrict__ counts, int* __restrict__ offs, int* __restrict__ cursor){
  __shared__ int part[256];
  int t = threadIdx.x;
  int sum = 0;
  for (int k = 0; k < 40; ++k){
    int idx = t * 40 + k;
    if (idx < N_ATOMS) sum += counts[idx];
  }
  part[t] = sum;
  __syncthreads();
  if (t == 0){
    int run = 0;
    for (int q = 0; q < 256; ++q){ int tmp = part[q]; part[q] = run; run += tmp; }
  }
  __syncthreads();
  int run = part[t];
  for (int k = 0; k < 40; ++k){
    int idx = t * 40 + k;
    if (idx < N_ATOMS){ offs[idx] = run; cursor[idx] = run; run += counts[idx]; }
  }
  if (t == 0) offs[N_ATOMS] = P_PAIRS;
}

__global__ void k_scatter(const int* __restrict__ pl, int* __restrict__ cursor, int* __restrict__ perm){
  int p = blockIdx.x * 256 + threadIdx.x;
  int i = pl[p];
  int pos = atomicAdd(&cursor[i], 1);
  perm[pos] = p;
}

// ------- per-pair edge model (sorted slots; fused filt; no spills) ---------
__global__ __launch_bounds__(256, 1) void k_pair(const float* __restrict__ h, const float* __restrict__ x,
    const int* __restrict__ pl, const int* __restrict__ perm, const float* __restrict__ Wf,
    u16* __restrict__ edge, float* __restrict__ logits, float* __restrict__ dirs){
  int tid = threadIdx.x;
  int s = blockIdx.x * 256 + tid;            // sorted slot
  int p = perm[s];
  int i = pl[p], j = pl[P_PAIRS + p];
  float hl[64];
  {
    const float4* a4 = (const float4*)(h + (size_t)i * 32);
    const float4* b4 = (const float4*)(h + (size_t)j * 32);
    #pragma unroll
    for (int q = 0; q < 8; ++q){
      float4 t = a4[q];
      hl[q*4+0] = t.x; hl[q*4+1] = t.y; hl[q*4+2] = t.z; hl[q*4+3] = t.w;
    }
    #pragma unroll
    for (int q = 0; q < 8; ++q){
      float4 t = b4[q];
      hl[32+q*4+0] = t.x; hl[32+q*4+1] = t.y; hl[32+q*4+2] = t.z; hl[32+q*4+3] = t.w;
    }
  }
  float r0 = x[j*3+0] - x[i*3+0];
  float r1 = x[j*3+1] - x[i*3+1];
  float r2 = x[j*3+2] - x[i*3+2];
  float d = sqrtf(r0*r0 + r1*r1 + r2*r2);
  float rinv = 1.f / (d + 1e-5f);
  dirs[s*3+0] = r0*rinv; dirs[s*3+1] = r1*rinv; dirs[s*3+2] = r2*rinv;

  // u = b_e1 + h_cat @ WE1[0:64] + d * WE1[114]
  float u[32];
  #pragma unroll
  for (int o = 0; o < 32; ++o) u[o] = Wf[OFF_BE1 + o];
  for (int k = 0; k < 64; ++k){
    float ek = hl[k];
    const float* wr = Wf + OFF_WE1 + k * 32;
    #pragma unroll
    for (int o = 0; o < 32; ++o) u[o] += ek * wr[o];
  }
  {
    const float* wr = Wf + OFF_WE1 + 114 * 32;
    #pragma unroll
    for (int o = 0; o < 32; ++o) u[o] += d * wr[o];
  }
  // fused filt: per kk compute scalar filt, accumulate into u
  for (int kk = 0; kk < 50; ++kk){
    const float* wm = Wf + OFF_WMLP + kk * 64;   // transposed row, contiguous
    float dot = Wf[OFF_BMLP + kk];
    #pragma unroll
    for (int k = 0; k < 64; ++k) dot += hl[k] * wm[k];
    float c = (float)kk * (5.0f / 49.0f);
    float dd = d - c;
    float filt = dot * __expf(-10.0f * dd * dd);
    const float* we = Wf + OFF_WE1 + (64 + kk) * 32;
    #pragma unroll
    for (int o = 0; o < 32; ++o) u[o] += filt * we[o];
  }
  #pragma unroll
  for (int o = 0; o < 32; ++o) u[o] = siluf(u[o]);
  // edge = u @ w_e2 + b
  float eg[32];
  #pragma unroll
  for (int o = 0; o < 32; ++o) eg[o] = Wf[OFF_BE2 + o];
  #pragma unroll
  for (int k = 0; k < 32; ++k){
    const float* wr = Wf + OFF_WE2 + k * 32;
    #pragma unroll
    for (int o = 0; o < 32; ++o) eg[o] += u[k] * wr[o];
  }
  {
    u32 st[16];
    #pragma unroll
    for (int o = 0; o < 16; ++o)
      st[o] = (u32)f2b(eg[2*o]) | ((u32)f2b(eg[2*o+1]) << 16);
    #pragma unroll
    for (int q = 0; q < 4; ++q){
      uint4 vv; vv.x = st[4*q]; vv.y = st[4*q+1]; vv.z = st[4*q+2]; vv.w = st[4*q+3];
      *(uint4*)(edge + (size_t)s * 32 + q * 8) = vv;
    }
  }
  float lg[7];
  #pragma unroll
  for (int o = 0; o < 7; ++o) lg[o] = Wf[OFF_BATT + o];
  #pragma unroll
  for (int k = 0; k < 32; ++k){
    const float* wr = Wf + OFF_WATT + k * 7;
    #pragma unroll
    for (int o = 0; o < 7; ++o) lg[o] += eg[k] * wr[o];
  }
  #pragma unroll
  for (int o = 0; o < 7; ++o){
    float vv = lg[o];
    float cl = vv > 0.f ? vv : 2.f * expm1f(0.5f * vv);
    logits[s*7+o] = cl;
  }
}

// ---------------- segment softmax: 16-lane group per atom ----------------
__global__ __launch_bounds__(256) void k_att(const int* __restrict__ offs,
    const float* __restrict__ logits, float* __restrict__ atts){
  int a = blockIdx.x * 16 + (threadIdx.x >> 4);   // N = 625*16
  int lane = threadIdx.x & 15;
  int off = offs[a], end = offs[a+1];
  float m[7];
  #pragma unroll
  for (int hh = 0; hh < 7; ++hh) m[hh] = -1e30f;
  for (int s = off + lane; s < end; s += 16){
    #pragma unroll
    for (int hh = 0; hh < 7; ++hh) m[hh] = fmaxf(m[hh], logits[s*7+hh]);
  }
  #pragma unroll
  for (int hh = 0; hh < 7; ++hh){
    float v = m[hh];
    #pragma unroll
    for (int msk = 8; msk >= 1; msk >>= 1) v = fmaxf(v, __shfl_xor(v, msk));
    m[hh] = v;
  }
  float sm[7] = {0,0,0,0,0,0,0};
  for (int s = off + lane; s < end; s += 16){
    #pragma unroll
    for (int hh = 0; hh < 7; ++hh){
      float e = __expf(logits[s*7+hh] - m[hh]);
      sm[hh] += e;
      atts[s*7+hh] = e;
    }
  }
  #pragma unroll
  for (int hh = 0; hh < 7; ++hh){
    float v = sm[hh];
    #pragma unroll
    for (int msk = 8; msk >= 1; msk >>= 1) v += __shfl_xor(v, msk);
    sm[hh] = 1.f / v;
  }
  for (int s = off + lane; s < end; s += 16){
    #pragma unroll
    for (int hh = 0; hh < 7; ++hh) atts[s*7+hh] *= sm[hh];
  }
}

// ---------------- MFMA GEMM -> xmix (no atomics) ----------------
#define G3_BS   10240
#define G3_EL   28160
#define G3_AL   36352
#define G3_TOT  59392

__global__ __launch_bounds__(256) void k_gemm3(const u16* __restrict__ edge,
    const float* __restrict__ atts, const u16* __restrict__ BT, u16* __restrict__ xmix){
  __shared__ __attribute__((aligned(16))) char smem[G3_TOT];
  u16*   As = (u16*)smem;
  u16*   Bs = (u16*)(smem + G3_BS);
  u16*   eL = (u16*)(smem + G3_EL);
  float* aL = (float*)(smem + G3_AL);
  int tid = threadIdx.x;
  int wave = tid >> 6, lane = tid & 63, l15 = lane & 15, quad = lane >> 4;
  int row0 = blockIdx.x * 128;

  for (int e = tid; e < 896; e += 256) aL[e] = atts[(size_t)row0*7 + e];
  for (int e = tid; e < 512; e += 256){
    int r = e >> 2, q = e & 3;
    *(uint4*)(eL + r*32 + q*8) = *(const uint4*)(edge + (size_t)(row0 + r)*32 + q*8);
  }
  floatx4 acc[2][14];
  #pragma unroll
  for (int mt = 0; mt < 2; ++mt)
    #pragma unroll
    for (int nt = 0; nt < 14; ++nt)
      acc[mt][nt] = (floatx4){0.f, 0.f, 0.f, 0.f};
  __syncthreads();

  for (int kt = 0; kt < 7; ++kt){
    int kk = kt * 32;
    for (int e = tid; e < 896; e += 256){
      int r = e >> 2, q = e & 3;
      *(uint4*)(Bs + r*40 + q*8) = *(const uint4*)(BT + (size_t)r*224 + kk + q*8);
    }
    for (int e = tid; e < 2048; e += 256){
      int r = e >> 4, c2 = (e & 15) * 2;
      int kc = kk + c2;
      int f0 = kc / 7,  h0 = kc - f0 * 7;
      int kc1 = kc + 1;
      int f1 = kc1 / 7, h1 = kc1 - f1 * 7;
      float v0 = b2f(eL[r*32 + f0]) * aL[r*7 + h0];
      float v1 = b2f(eL[r*32 + f1]) * aL[r*7 + h1];
      ((u32*)As)[r*20 + (e & 15)] = (u32)f2b(v0) | ((u32)f2b(v1) << 16);
    }
    __syncthreads();
    short8 a0 = *(const short8*)(As + (wave*32 + l15)*40 + quad*8);
    short8 a1 = *(const short8*)(As + (wave*32 + 16 + l15)*40 + quad*8);
    #pragma unroll
    for (int nt = 0; nt < 14; ++nt){
      short8 b = *(const short8*)(Bs + (nt*16 + l15)*40 + quad*8);
      acc[0][nt] = __builtin_amdgcn_mfma_f32_16x16x32_bf16(a0, b, acc[0][nt], 0, 0, 0);
      acc[1][nt] = __builtin_amdgcn_mfma_f32_16x16x32_bf16(a1, b, acc[1][nt], 0, 0, 0);
    }
    __syncthreads();
  }
  u16* xt = (u16*)smem;
  #pragma unroll
  for (int mt = 0; mt < 2; ++mt)
    #pragma unroll
    for (int nt = 0; nt < 14; ++nt)
      #pragma unroll
      for (int reg = 0; reg < 4; ++reg){
        int r = wave*32 + mt*16 + quad*4 + reg;
        int c = nt*16 + l15;
        float vv = acc[mt][nt][reg];
        vv = fminf(fmaxf(vv, -15.f), 15.f);
        float e2 = __expf(2.f * vv);
        xt[r*232 + c] = f2b((e2 - 1.f) / (e2 + 1.f));
      }
  __syncthreads();
  for (int e = tid; e < 3584; e += 256){
    int r = e / 28, w = e - r * 28;
    *(uint4*)(xmix + (size_t)(row0 + r)*224 + w*8) = *(const uint4*)(xt + r*232 + w*8);
  }
}

// ---------------- final: wave per atom ----------------
__global__ __launch_bounds__(256) void k_final4(const float* __restrict__ h, const float* __restrict__ x,
    const float* __restrict__ v, const float* __restrict__ Wf, const int* __restrict__ offs,
    const u16* __restrict__ edge, const float* __restrict__ atts, const float* __restrict__ dirs,
    const u16* __restrict__ xmix, float* __restrict__ out){
  __shared__ float s_nsq[4][224];
  __shared__ float s_hsem[4][224];
  __shared__ float s_u1[4][32], s_sp[4][32], s_g[4][32], s_un[4][32];
  int wv_ = threadIdx.x >> 6, lane = threadIdx.x & 63;
  int a = blockIdx.x * 4 + wv_;                 // N = 2500*4
  int off = offs[a], end = offs[a+1];
  int cnt = end - off;
  float inv = 1.f / fmaxf((float)cnt, 1.f);
  int cbase = lane * 4;
  float c0[4] = {0,0,0,0}, c1[4] = {0,0,0,0}, c2[4] = {0,0,0,0}, hs[4] = {0,0,0,0};
  int f_[4], hh_[4];
  #pragma unroll
  for (int j = 0; j < 4; ++j){
    int c = cbase + j;
    int cf = (c < 224) ? c : 0;
    f_[j] = cf / 7; hh_[j] = cf - f_[j] * 7;
  }
  if (lane < 56){
    for (int s = off; s < end; ++s){
      uint2 xm2 = *(const uint2*)(xmix + (size_t)s * 224 + cbase);
      float d0 = dirs[s*3+0], d1 = dirs[s*3+1], d2 = dirs[s*3+2];
      u16 xs[4] = {(u16)(xm2.x & 0xFFFFu), (u16)(xm2.x >> 16),
                   (u16)(xm2.y & 0xFFFFu), (u16)(xm2.y >> 16)};
      #pragma unroll
      for (int j = 0; j < 4; ++j){
        float xm = b2f(xs[j]);
        c0[j] += d0 * xm; c1[j] += d1 * xm; c2[j] += d2 * xm;
        hs[j] += b2f(edge[(size_t)s*32 + f_[j]]) * atts[s*7 + hh_[j]];
      }
    }
  }
  float pv0 = 0.f, pv1 = 0.f, pv2 = 0.f;
  if (lane < 56){
    #pragma unroll
    for (int j = 0; j < 4; ++j){
      int c = cbase + j;
      float cm0 = c0[j]*inv, cm1 = c1[j]*inv, cm2 = c2[j]*inv;
      s_nsq[wv_][c] = cm0*cm0 + cm1*cm1 + cm2*cm2;
      s_hsem[wv_][c] = hs[j];
      float wvx = Wf[OFF_WVMIX + c];
      pv0 += wvx*cm0; pv1 += wvx*cm1; pv2 += wvx*cm2;
    }
  }
  #pragma unroll
  for (int m = 32; m >= 1; m >>= 1){
    pv0 += __shfl_xor(pv0, m); pv1 += __shfl_xor(pv1, m); pv2 += __shfl_xor(pv2, m);
  }
  __syncthreads();
  if (lane < 32){
    float u = Wf[OFF_BP1 + lane];
    for (int c = 0; c < 224; ++c) u += s_nsq[wv_][c] * Wf[OFF_WP1 + c*32 + lane];
    s_u1[wv_][lane] = siluf(u);
    float g = Wf[OFF_BV1 + lane];
    #pragma unroll
    for (int k = 0; k < 32; ++k) g += h[a*32+k] * Wf[OFF_WV1 + k*32 + lane];
    s_g[wv_][lane] = siluf(g);
  }
  __syncthreads();
  float zpart = (lane < 32) ? s_g[wv_][lane] * Wf[OFF_WV2 + lane] : 0.f;
  #pragma unroll
  for (int m = 32; m >= 1; m >>= 1) zpart += __shfl_xor(zpart, m);
  float sc = 2.f / (1.f + __expf(-zpart));
  if (lane < 32){
    float u = Wf[OFF_BP2 + lane];
    #pragma unroll
    for (int k = 0; k < 32; ++k) u += s_u1[wv_][k] * Wf[OFF_WP2 + k*32 + lane];
    s_sp[wv_][lane] = siluf(u);
  }
  __syncthreads();
  if (lane < 32){
    float u = Wf[OFF_BN1 + lane];
    #pragma unroll
    for (int k = 0; k < 32; ++k) u += h[a*32+k] * Wf[OFF_WN1 + k*32 + lane];
    for (int c = 0; c < 224; ++c) u += s_hsem[wv_][c] * Wf[OFF_WN1 + (32 + c)*32 + lane];
    #pragma unroll
    for (int k = 0; k < 32; ++k) u += s_sp[wv_][k] * Wf[OFF_WN1 + (256 + k)*32 + lane];
    s_un[wv_][lane] = siluf(u);
  }
  __syncthreads();
  if (lane < 32){
    float u = Wf[OFF_BN2 + lane];
    #pragma unroll
    for (int k = 0; k < 32; ++k) u += s_un[wv_][k] * Wf[OFF_WN2 + k*32 + lane];
    out[a*32+lane] = h[a*32+lane] + siluf(u);
  }
  if (lane < 3){
    float vup = sc * v[a*3+lane] + ((lane == 0) ? pv0 : (lane == 1) ? pv1 : pv2);
    float xup = x[a*3+lane] + vup;
    out[N_ATOMS*32 + a*3 + lane] = xup;
    out[N_ATOMS*32 + N_ATOMS*3 + a*3 + lane] = vup;
  }
}

// ---------------- workspace layout (~93 MB, proven) ----------------
static constexpr size_t al256(size_t x){ return (x + 255) & ~(size_t)255; }
static constexpr size_t WS_FLAGS   = 0;
static constexpr size_t WS_COUNTS  = al256(WS_FLAGS + 8);
static constexpr size_t WS_OFFSETS = al256(WS_COUNTS + (size_t)N_ATOMS * 4);
static constexpr size_t WS_CURSOR  = al256(WS_OFFSETS + (size_t)(N_ATOMS + 1) * 4);
static constexpr size_t WS_PERM    = al256(WS_CURSOR + (size_t)N_ATOMS * 4);
static constexpr size_t WS_PLI     = al256(WS_PERM + (size_t)P_PAIRS * 4);
static constexpr size_t WS_HF      = al256(WS_PLI + (size_t)2 * P_PAIRS * 4);
static constexpr size_t WS_XF      = al256(WS_HF + (size_t)N_ATOMS * 32 * 4);
static constexpr size_t WS_VF      = al256(WS_XF + (size_t)N_ATOMS * 3 * 4);
static constexpr size_t WS_WF      = al256(WS_VF + (size_t)N_ATOMS * 3 * 4);
static constexpr size_t WS_WT      = al256(WS_WF + (size_t)WF_TOTAL * 4);
static constexpr size_t WS_EDGE    = al256(WS_WT + (size_t)224 * 224 * 2);
static constexpr size_t WS_ATTS    = al256(WS_EDGE + (size_t)P_PAIRS * 32 * 2);
static constexpr size_t WS_DIRS    = al256(WS_ATTS + (size_t)P_PAIRS * 7 * 4);
static constexpr size_t WS_LOGITS  = al256(WS_DIRS + (size_t)P_PAIRS * 3 * 4);
static constexpr size_t WS_END     = WS_LOGITS + (size_t)P_PAIRS * 224 * 2;   // xmix aliases logits

extern "C" void kernel_launch(void* const* d_in, const int* in_sizes, int n_in,
                              void* d_out, int out_size, void* d_ws, size_t ws_size,
                              hipStream_t stream){
  (void)in_sizes; (void)n_in;
  if (out_size != 380000 || ws_size < WS_END){
    k_code<<<1, 64, 0, stream>>>((float*)d_out, 14000.f);
    return;
  }
  char* ws = (char*)d_ws;
  int*   flags  = (int*)(ws + WS_FLAGS);
  int*   counts = (int*)(ws + WS_COUNTS);
  int*   offs   = (int*)(ws + WS_OFFSETS);
  int*   cursor = (int*)(ws + WS_CURSOR);
  int*   perm   = (int*)(ws + WS_PERM);
  int*   pli    = (int*)(ws + WS_PLI);
  float* hf     = (float*)(ws + WS_HF);
  float* xf     = (float*)(ws + WS_XF);
  float* vf     = (float*)(ws + WS_VF);
  float* Wf     = (float*)(ws + WS_WF);
  u16*   wT     = (u16*)(ws + WS_WT);
  u16*   edge   = (u16*)(ws + WS_EDGE);
  float* atts   = (float*)(ws + WS_ATTS);
  float* dirs   = (float*)(ws + WS_DIRS);
  float* logits = (float*)(ws + WS_LOGITS);
  u16*   xmix   = (u16*)(ws + WS_LOGITS);     // alias; logits dead after k_att

  hipMemsetAsync(counts, 0, (size_t)N_ATOMS * 4, stream);
  k_detect<<<1, 64, 0, stream>>>((const u32*)d_in[0], (const u32*)d_in[3], flags);
  k_norm<<<(700000 + 255) / 256, 256, 0, stream>>>(d_in[0], d_in[1], d_in[2], d_in[3],
                                                   flags, hf, xf, vf, pli);
  k_convert<<<(WF_TOTAL + 255) / 256, 256, 0, stream>>>(
      d_in[4],  d_in[5],  d_in[6],  d_in[7],  d_in[8],  d_in[9],  d_in[10], d_in[11],
      d_in[12], d_in[13], d_in[14], d_in[15], d_in[16], d_in[17], d_in[18], d_in[19],
      d_in[20], d_in[21], d_in[22], d_in[24], flags, Wf);
  k_transpose<<<(224 * 224 + 255) / 256, 256, 0, stream>>>(d_in[23], flags, wT);
  k_hist<<<P_PAIRS / 256, 256, 0, stream>>>(pli, counts);
  k_scan<<<1, 256, 0, stream>>>(counts, offs, cursor);
  k_scatter<<<P_PAIRS / 256, 256, 0, stream>>>(pli, cursor, perm);
  k_pair<<<P_PAIRS / 256, 256, 0, stream>>>(hf, xf, pli, perm, Wf, edge, logits, dirs);
  k_att<<<N_ATOMS / 16, 256, 0, stream>>>(offs, logits, atts);
  k_gemm3<<<P_PAIRS / 128, 256, 0, stream>>>(edge, atts, wT, xmix);
  k_final4<<<N_ATOMS / 4, 256, 0, stream>>>(hf, xf, vf, Wf, offs, edge, atts, dirs, xmix, (float*)d_out);
}